// Round 10
// baseline (836.943 us; speedup 1.0000x reference)
//
#include <hip/hip_runtime.h>
#include <math.h>

#define EMBED 768
#define HEADS 8
#define HDIM  96
#define NEG_MASK (-1.0e30f)

typedef unsigned short u16;
typedef unsigned int   u32;

typedef __attribute__((ext_vector_type(4))) float f32x4;
typedef __attribute__((ext_vector_type(8))) short short8;

__device__ __forceinline__ float bf2f(u16 u) {
    return __uint_as_float(((u32)u) << 16);
}
__device__ __forceinline__ u16 f2bf(float f) {
    u32 x = __float_as_uint(f);
    u32 r = (x + 0x7fffu + ((x >> 16) & 1u)) >> 16;
    return (u16)r;
}
__device__ __forceinline__ void unpack2(u32 w, float& lo, float& hi) {
    lo = __uint_as_float(w << 16);
    hi = __uint_as_float(w & 0xffff0000u);
}
__device__ __forceinline__ float wget(const void* p, size_t i, int wf) {
    return wf ? ((const float*)p)[i] : bf2f(((const u16*)p)[i]);
}
// LDS bank swizzle: u16 offset of 8-wide k-chunk g within a 32-u16 row r.
__device__ __forceinline__ int bswz(int r, int g) {
    return ((g ^ (r & 3) ^ ((r >> 2) & 3) ^ ((r >> 4) & 3)) << 3);
}
// Barrier that publishes LDS but does NOT drain vmcnt (T4 counted-vmcnt).
// __syncthreads() would emit s_waitcnt vmcnt(0) before s_barrier, killing
// cross-barrier in-flight global loads. lgkmcnt(0) publishes this wave's LDS
// writes; the barrier makes all waves' writes visible. Register-destination
// global loads are safe in flight (their counted vmcnt wait lands at use).
__device__ __forceinline__ void lds_barrier() {
    __builtin_amdgcn_sched_barrier(0);
    asm volatile("s_waitcnt lgkmcnt(0)" ::: "memory");
    __builtin_amdgcn_s_barrier();
    __builtin_amdgcn_sched_barrier(0);
}

// ---------------- detection ----------------
__global__ __launch_bounds__(64) void detect_kernel(const u16* __restrict__ x,
                                                    const int* __restrict__ el,
                                                    const int* __restrict__ usp,
                                                    int* __restrict__ blk) {
    int lane = threadIdx.x;
    int cnt = 0;
    for (int i = lane; i < 4096; i += 64) {
        u32 e = (x[i] >> 7) & 0xFFu;
        if (e >= 0xC0u) cnt++;
    }
#pragma unroll
    for (int off = 32; off > 0; off >>= 1) cnt += __shfl_xor(cnt, off, 64);
    if (lane == 0) {
        blk[0] = (cnt > 32) ? 1 : 0;
        bool i64 = (el[1] == 0) && (el[3] == 0) && (el[5] == 0) && (el[7] == 0);
        for (int b = 0; b < 8; b++) blk[1 + b] = i64 ? el[2 * b] : el[b];
        blk[9] = usp[0];
    }
}

// ---------------- copies ----------------
__global__ void wire_to_f32(const void* __restrict__ in, size_t ioff,
                            float* __restrict__ out, int n,
                            const int* __restrict__ blk) {
    int i = blockIdx.x * blockDim.x + threadIdx.x;
    int wf = blk[0];
    if (i < n) out[i] = wget(in, ioff + (size_t)i, wf);
}
__global__ void wire_copy(const void* __restrict__ in, void* __restrict__ out,
                          int n, const int* __restrict__ blk) {
    int i = blockIdx.x * blockDim.x + threadIdx.x;
    int wf = blk[0];
    if (i < n) {
        if (wf) ((float*)out)[i] = ((const float*)in)[i];
        else    ((u16*)out)[i]   = ((const u16*)in)[i];
    }
}
__global__ void f32_to_out(const float* __restrict__ in, void* __restrict__ out,
                           size_t ooff, int n, const int* __restrict__ blk) {
    int i = blockIdx.x * blockDim.x + threadIdx.x;
    int wf = blk[0];
    if (i < n) {
        if (wf) ((float*)out)[ooff + i] = in[i];
        else    ((u16*)out)[ooff + i]   = f2bf(in[i]);
    }
}

// ---------------- weight transpose: W[K][N] (f32|bf16) -> WT[N][K] bf16 ----
__global__ __launch_bounds__(256) void wtrans_kernel(const void* __restrict__ W, size_t woff,
                                                     int ldw, int K,
                                                     u16* __restrict__ WT,
                                                     const int* __restrict__ blk) {
    __shared__ u16 T[64][65];   // T[n_local][k_local]
    int wf = blk[0];
    int n0 = blockIdx.x * 64, k0 = blockIdx.y * 64;
    int tid = threadIdx.x;
    int tr = tid >> 4, tc4 = (tid & 15) * 4;
#pragma unroll
    for (int i = 0; i < 4; i++) {
        int k = tr + i * 16;
        if (wf) {
            const float* src = (const float*)W + woff + (size_t)(k0 + k) * ldw + n0 + tc4;
            float4 f = *(const float4*)src;
            T[tc4 + 0][k] = f2bf(f.x); T[tc4 + 1][k] = f2bf(f.y);
            T[tc4 + 2][k] = f2bf(f.z); T[tc4 + 3][k] = f2bf(f.w);
        } else {
            const u16* src = (const u16*)W + woff + (size_t)(k0 + k) * ldw + n0 + tc4;
            uint2 u = *(const uint2*)src;
            T[tc4 + 0][k] = (u16)(u.x & 0xffffu); T[tc4 + 1][k] = (u16)(u.x >> 16);
            T[tc4 + 2][k] = (u16)(u.y & 0xffffu); T[tc4 + 3][k] = (u16)(u.y >> 16);
        }
    }
    __syncthreads();
#pragma unroll
    for (int i = 0; i < 4; i++) {
        int n = tr + i * 16;
        u32 w0 = (u32)T[n][tc4 + 0] | ((u32)T[n][tc4 + 1] << 16);
        u32 w1 = (u32)T[n][tc4 + 2] | ((u32)T[n][tc4 + 3] << 16);
        *(uint2*)(WT + (size_t)(n0 + n) * K + k0 + tc4) = make_uint2(w0, w1);
    }
}

// ---------------- LayerNorm ----------------
__global__ __launch_bounds__(256) void ln_kernel(const void* __restrict__ in,
                                                 size_t ioff, int sel,
                                                 const void* __restrict__ g,
                                                 const void* __restrict__ b,
                                                 u16* __restrict__ out,
                                                 const int* __restrict__ blk) {
    int wf = blk[0];
    int row = blockIdx.x, tid = threadIdx.x;
    size_t base = ioff + (size_t)row * EMBED;
    float v[3];
#pragma unroll
    for (int e = 0; e < 3; e++) {
        size_t idx = base + tid + e * 256;
        v[e] = (sel == 0) ? ((const float*)in)[idx] : wget(in, idx, wf);
    }
    float s = v[0] + v[1] + v[2];
    float q = v[0] * v[0] + v[1] * v[1] + v[2] * v[2];
#pragma unroll
    for (int off = 32; off > 0; off >>= 1) {
        s += __shfl_xor(s, off, 64);
        q += __shfl_xor(q, off, 64);
    }
    __shared__ float sb[8];
    int wid = tid >> 6, lane = tid & 63;
    if (lane == 0) { sb[wid] = s; sb[4 + wid] = q; }
    __syncthreads();
    if (tid == 0) {
        sb[0] = sb[0] + sb[1] + sb[2] + sb[3];
        sb[4] = sb[4] + sb[5] + sb[6] + sb[7];
    }
    __syncthreads();
    float mean = sb[0] * (1.0f / EMBED);
    float var  = sb[4] * (1.0f / EMBED) - mean * mean;
    float rs   = rsqrtf(var + 1e-5f);
    size_t obase = (size_t)row * EMBED;
#pragma unroll
    for (int e = 0; e < 3; e++) {
        int col = tid + e * 256;
        out[obase + col] = f2bf((v[e] - mean) * rs * wget(g, col, wf) + wget(b, col, wf));
    }
}

// ---------------- legacy VALU GEMM (tier-C fallback: handles N=192) ----------------
__global__ __launch_bounds__(256) void gemm_kernel(const u16* __restrict__ A,
                                                   const void* __restrict__ W,
                                                   size_t woff, int ldw,
                                                   const void* __restrict__ bias, int boff,
                                                   void* __restrict__ Cv, size_t coff,
                                                   int M, int N, int K, int flags,
                                                   int tcmode, const int* __restrict__ blk) {
    __shared__ float As[16][64];
    __shared__ float Bs[16][64];
    int wf = blk[0];
    int tid = threadIdx.x;
    int tx = tid & 15, ty = tid >> 4;
    int row0 = blockIdx.y * 64, col0 = blockIdx.x * 64;
    float acc[4][4] = {};
    int ar = tid >> 2, ac4 = tid & 3;
    int br = tid >> 4, bc4 = tid & 15;

    for (int kb = 0; kb < K; kb += 16) {
        {
            uint2 u = *(const uint2*)(A + (size_t)(row0 + ar) * K + kb + ac4 * 4);
            float a0, a1, a2, a3;
            unpack2(u.x, a0, a1); unpack2(u.y, a2, a3);
            As[ac4 * 4 + 0][ar] = a0; As[ac4 * 4 + 1][ar] = a1;
            As[ac4 * 4 + 2][ar] = a2; As[ac4 * 4 + 3][ar] = a3;
        }
        {
            size_t off = woff + (size_t)(kb + br) * ldw + col0 + bc4 * 4;
            if (wf) {
                float4 u = *(const float4*)((const float*)W + off);
                Bs[br][bc4 * 4 + 0] = u.x; Bs[br][bc4 * 4 + 1] = u.y;
                Bs[br][bc4 * 4 + 2] = u.z; Bs[br][bc4 * 4 + 3] = u.w;
            } else {
                uint2 u = *(const uint2*)((const u16*)W + off);
                float b0, b1, b2, b3;
                unpack2(u.x, b0, b1); unpack2(u.y, b2, b3);
                Bs[br][bc4 * 4 + 0] = b0; Bs[br][bc4 * 4 + 1] = b1;
                Bs[br][bc4 * 4 + 2] = b2; Bs[br][bc4 * 4 + 3] = b3;
            }
        }
        __syncthreads();
#pragma unroll
        for (int kk = 0; kk < 16; kk++) {
            float4 a = *(const float4*)&As[kk][ty * 4];
            float4 b = *(const float4*)&Bs[kk][tx * 4];
            float av[4] = {a.x, a.y, a.z, a.w};
            float bv[4] = {b.x, b.y, b.z, b.w};
#pragma unroll
            for (int i = 0; i < 4; i++)
#pragma unroll
                for (int j = 0; j < 4; j++)
                    acc[i][j] += av[i] * bv[j];
        }
        __syncthreads();
    }

#pragma unroll
    for (int i = 0; i < 4; i++) {
        int m = row0 + ty * 4 + i;
#pragma unroll
        for (int j = 0; j < 4; j++) {
            int n = col0 + tx * 4 + j;
            float v = acc[i][j];
            if (flags & 1) v += wget(bias, boff + n, wf);
            if (flags & 2) v = 0.5f * v * (1.0f + erff(v * 0.70710678118654752f));
            size_t idx = coff + (size_t)m * N + n;
            if (tcmode == 0) {
                ((float*)Cv)[idx] += v;
            } else if (tcmode == 1) {
                ((u16*)Cv)[idx] = f2bf(v);
            } else {
                if (wf) ((float*)Cv)[idx] += v;
                else { u16* p = (u16*)Cv; p[idx] = f2bf(v + bf2f(p[idx])); }
            }
        }
    }
}

// ---------------- MFMA GEMM (tier-B, reg-staged scatter B; legacy) ----------
__global__ __launch_bounds__(256) void gemm_mfma(const u16* __restrict__ A,
                                                 const void* __restrict__ W,
                                                 size_t woff, int ldw,
                                                 const void* __restrict__ bias, int boff,
                                                 void* __restrict__ Cv, size_t coff,
                                                 int M, int N, int K, int flags,
                                                 int tcmode, const int* __restrict__ blk) {
    __shared__ __align__(16) u16 As[128 * 32];
    __shared__ __align__(16) u16 Bs[128 * 32];
    int wf = blk[0];
    int tid = threadIdx.x;
    int wave = tid >> 6, lane = tid & 63;
    int x = lane & 15, g = lane >> 4;
    int wm = wave >> 1, wn = wave & 1;
    int row0 = blockIdx.y * 128, col0 = blockIdx.x * 128;

    int ar  = tid >> 1, ah = tid & 1;
    int bk  = tid >> 3, bn0 = (tid & 7) * 16;

    f32x4 acc[4][4];
#pragma unroll
    for (int i = 0; i < 4; i++)
#pragma unroll
        for (int j = 0; j < 4; j++) acc[i][j] = (f32x4){0.f, 0.f, 0.f, 0.f};

    for (int kb = 0; kb < K; kb += 32) {
        {
            const u16* asrc = A + (size_t)(row0 + ar) * K + kb + ah * 16;
            uint4 a0 = *(const uint4*)asrc;
            uint4 a1 = *(const uint4*)(asrc + 8);
            *(uint4*)&As[ar * 32 + bswz(ar, ah * 2 + 0)] = a0;
            *(uint4*)&As[ar * 32 + bswz(ar, ah * 2 + 1)] = a1;
        }
        {
            u16 bv[16];
            if (wf) {
                const float* wsrc = (const float*)W + woff + (size_t)(kb + bk) * ldw + col0 + bn0;
#pragma unroll
                for (int i = 0; i < 16; i += 4) {
                    float4 f = *(const float4*)(wsrc + i);
                    bv[i + 0] = f2bf(f.x); bv[i + 1] = f2bf(f.y);
                    bv[i + 2] = f2bf(f.z); bv[i + 3] = f2bf(f.w);
                }
            } else {
                const u16* wsrc = (const u16*)W + woff + (size_t)(kb + bk) * ldw + col0 + bn0;
                ((uint4*)bv)[0] = *(const uint4*)wsrc;
                ((uint4*)bv)[1] = *(const uint4*)(wsrc + 8);
            }
            int kg = bk >> 3, kl = bk & 7;
#pragma unroll
            for (int i = 0; i < 16; i++)
                Bs[(bn0 + i) * 32 + bswz(bn0 + i, kg) + kl] = bv[i];
        }
        __syncthreads();

        short8 af[4], bf[4];
#pragma unroll
        for (int mt = 0; mt < 4; mt++) {
            int r = wm * 64 + mt * 16 + x;
            af[mt] = *(const short8*)&As[r * 32 + bswz(r, g)];
        }
#pragma unroll
        for (int nt = 0; nt < 4; nt++) {
            int n = wn * 64 + nt * 16 + x;
            bf[nt] = *(const short8*)&Bs[n * 32 + bswz(n, g)];
        }
#pragma unroll
        for (int mt = 0; mt < 4; mt++)
#pragma unroll
            for (int nt = 0; nt < 4; nt++)
                acc[mt][nt] = __builtin_amdgcn_mfma_f32_16x16x32_bf16(af[mt], bf[nt], acc[mt][nt], 0, 0, 0);
        __syncthreads();
    }

#pragma unroll
    for (int mt = 0; mt < 4; mt++) {
#pragma unroll
        for (int nt = 0; nt < 4; nt++) {
#pragma unroll
            for (int r = 0; r < 4; r++) {
                int m = row0 + wm * 64 + mt * 16 + g * 4 + r;
                int n = col0 + wn * 64 + nt * 16 + x;
                float v = acc[mt][nt][r];
                if (flags & 1) v += wget(bias, boff + n, wf);
                if (flags & 2) v = 0.5f * v * (1.0f + erff(v * 0.70710678118654752f));
                size_t idx = coff + (size_t)m * N + n;
                if (tcmode == 0) {
                    ((float*)Cv)[idx] += v;
                } else if (tcmode == 1) {
                    ((u16*)Cv)[idx] = f2bf(v);
                } else {
                    if (wf) ((float*)Cv)[idx] += v;
                    else { u16* p = (u16*)Cv; p[idx] = f2bf(v + bf2f(p[idx])); }
                }
            }
        }
    }
}

// ---------------- MFMA GEMM v4: 64x128 tile, pre-transposed bf16 weights,
// depth-2 register pipeline, lgkmcnt-only barrier (counted vmcnt, T4).
__global__ __launch_bounds__(256) void gemm_mfma_t(const u16* __restrict__ A,
                                                   const u16* __restrict__ BT,
                                                   const void* __restrict__ bias, int boff,
                                                   void* __restrict__ Cv, size_t coff,
                                                   int M, int N, int K, int flags,
                                                   int tcmode, const int* __restrict__ blk) {
    __shared__ __align__(16) u16 As[2][64 * 32];
    __shared__ __align__(16) u16 Bs[2][128 * 32];
    int wf = blk[0];
    int tid = threadIdx.x;
    int wave = tid >> 6, lane = tid & 63;
    int x = lane & 15, g = lane >> 4;
    int wm = wave >> 1, wn = wave & 1;
    int row0 = blockIdx.y * 64, col0 = blockIdx.x * 128;
    int KS = gridDim.z, kz = blockIdx.z;
    int Kc = K / KS;

    int ar = tid >> 2, ac = tid & 3;
    const u16* aptr = A + (size_t)(row0 + ar) * K + kz * Kc + ac * 8;
    int awo = ar * 32 + bswz(ar, ac);
    int br = tid >> 1, bh = tid & 1;
    const u16* bptr = BT + (size_t)(col0 + br) * K + kz * Kc + bh * 16;
    int bwo0 = br * 32 + bswz(br, 2 * bh);
    int bwo1 = br * 32 + bswz(br, 2 * bh + 1);

    int ra[2], rb[4];
#pragma unroll
    for (int mt = 0; mt < 2; mt++) {
        int r = wm * 32 + mt * 16 + x;
        ra[mt] = r * 32 + bswz(r, g);
    }
#pragma unroll
    for (int nt = 0; nt < 4; nt++) {
        int n = wn * 64 + nt * 16 + x;
        rb[nt] = n * 32 + bswz(n, g);
    }

    f32x4 acc[2][4];
#pragma unroll
    for (int i = 0; i < 2; i++)
#pragma unroll
        for (int j = 0; j < 4; j++) acc[i][j] = (f32x4){0.f, 0.f, 0.f, 0.f};

    int nsteps = Kc >> 5;

    *(uint4*)&As[0][awo]  = *(const uint4*)aptr;
    *(uint4*)&Bs[0][bwo0] = *(const uint4*)bptr;
    *(uint4*)&Bs[0][bwo1] = *(const uint4*)(bptr + 8);
    uint4 s0a = {}, s0b0 = {}, s0b1 = {};
    uint4 s1a = {}, s1b0 = {}, s1b1 = {};
    if (nsteps > 1) {
        aptr += 32; bptr += 32;
        s1a  = *(const uint4*)aptr;
        s1b0 = *(const uint4*)bptr; s1b1 = *(const uint4*)(bptr + 8);
    }
    lds_barrier();

#define GSTEP(S, LA, LB0, LB1, WA, WB0, WB1)                                      \
    {                                                                             \
        if ((S) + 2 < nsteps) {                                                   \
            aptr += 32; bptr += 32;                                               \
            LA  = *(const uint4*)aptr;                                            \
            LB0 = *(const uint4*)bptr; LB1 = *(const uint4*)(bptr + 8);           \
        }                                                                         \
        short8 af[2], bfr[4];                                                     \
        _Pragma("unroll")                                                         \
        for (int mt = 0; mt < 2; mt++)                                            \
            af[mt] = *(const short8*)&As[(S) & 1][ra[mt]];                        \
        _Pragma("unroll")                                                         \
        for (int nt = 0; nt < 4; nt++)                                            \
            bfr[nt] = *(const short8*)&Bs[(S) & 1][rb[nt]];                       \
        _Pragma("unroll")                                                         \
        for (int mt = 0; mt < 2; mt++)                                            \
            _Pragma("unroll")                                                     \
            for (int nt = 0; nt < 4; nt++)                                        \
                acc[mt][nt] = __builtin_amdgcn_mfma_f32_16x16x32_bf16(            \
                    af[mt], bfr[nt], acc[mt][nt], 0, 0, 0);                       \
        if ((S) + 1 < nsteps) {                                                   \
            int nb = (((S) & 1) ^ 1);                                             \
            *(uint4*)&As[nb][awo]  = WA;                                          \
            *(uint4*)&Bs[nb][bwo0] = WB0; *(uint4*)&Bs[nb][bwo1] = WB1;           \
            lds_barrier();                                                        \
        }                                                                         \
    }

    for (int s = 0; s < nsteps; s += 2) {
        GSTEP(s, s0a, s0b0, s0b1, s1a, s1b0, s1b1);
        if (s + 1 < nsteps)
            GSTEP(s + 1, s1a, s1b0, s1b1, s0a, s0b0, s0b1);
    }
#undef GSTEP

    bool kz0 = (kz == 0);
#pragma unroll
    for (int mt = 0; mt < 2; mt++) {
#pragma unroll
        for (int nt = 0; nt < 4; nt++) {
#pragma unroll
            for (int r = 0; r < 4; r++) {
                int m = row0 + wm * 32 + mt * 16 + g * 4 + r;
                int n = col0 + wn * 64 + nt * 16 + x;
                float v = acc[mt][nt][r];
                if ((flags & 1) && kz0) v += wget(bias, boff + n, wf);
                if (flags & 2) v = 0.5f * v * (1.0f + erff(v * 0.70710678118654752f));
                size_t idx = coff + (size_t)m * N + n;
                if (tcmode == 0) {
                    if (KS > 1) atomicAdd(&((float*)Cv)[idx], v);
                    else        ((float*)Cv)[idx] += v;
                } else if (tcmode == 1) {
                    ((u16*)Cv)[idx] = f2bf(v);
                } else {
                    if (wf) ((float*)Cv)[idx] += v;
                    else { u16* p = (u16*)Cv; p[idx] = f2bf(v + bf2f(p[idx])); }
                }
            }
        }
    }
}

// ---------------- flash attention v3: T14 async staging ----------------
// Round-6 shape (4 waves x 16 rows, grid (16,H,B)); el-skip REMOVED (measured
// net-negative: load imbalance > work saved). Per K-tile, the 6 global b128
// loads for tile t+1 are issued right after the staging barrier of tile t and
// consumed (counted vmcnt at ds_write) at the top of iteration t+1 — their
// ~300-900cy latency hides under QK^T+softmax+PV. Both barriers are
// lgkmcnt-only so the in-flight loads survive. s_setprio(1) wraps the MFMA
// clusters (T5). In-place safe (AO == Q).
__global__ __launch_bounds__(256) void attn_kernel(const u16* __restrict__ Q,
                                                   const u16* __restrict__ K,
                                                   const u16* __restrict__ V,
                                                   u16* __restrict__ AO,
                                                   int ldq, int ldk, int ldv, int ldo,
                                                   size_t qss, size_t kss, size_t oss,
                                                   const int* __restrict__ blk,
                                                   int bfix, int Lk, int is_self) {
    int bz   = (bfix < 0) ? blockIdx.z : 0;
    int bidx = (bfix < 0) ? blockIdx.z : bfix;
    const u16* Qp = Q + (size_t)bz * qss;
    const u16* Kp = K + (size_t)bz * kss;
    const u16* Vp = V + (size_t)bz * kss;
    u16* AOp = AO + (size_t)bz * oss;

    int hoff = blockIdx.y * HDIM;
    int i0 = blockIdx.x * 64;
    int tid = threadIdx.x;
    int wave = tid >> 6, lane = tid & 63;
    int x = lane & 15, g = lane >> 4;

    int elb = blk[1 + bidx];
    int el_q = elb * blk[9];
    int el_k = is_self ? el_q : elb;

    __shared__ __align__(16) u16 Ks[64 * 96];
    __shared__ __align__(16) u16 Vs[96 * 64];
    __shared__ __align__(16) u16 Ps[4][16 * 72];

    short8 qf[3];
    {
        const u16* qrow = Qp + (size_t)(i0 + wave * 16 + x) * ldq + hoff;
#pragma unroll
        for (int kc = 0; kc < 3; kc++)
            qf[kc] = *(const short8*)(qrow + kc * 32 + g * 8);
    }

    const f32x4 zero4 = {0.f, 0.f, 0.f, 0.f};
    f32x4 o[6];
#pragma unroll
    for (int dt = 0; dt < 6; dt++) o[dt] = zero4;
    float m[4], l[4];
#pragma unroll
    for (int r = 0; r < 4; r++) { m[r] = NEG_MASK; l[r] = 0.f; }

    bool qok[4];
#pragma unroll
    for (int r = 0; r < 4; r++) qok[r] = (i0 + wave * 16 + g * 4 + r) < el_q;

    const float scale = 0.10206207261596576f;  // 1/sqrt(96)
    u16* pw = &Ps[wave][0];

    // staging slots: 3 (row, chunk) pairs per thread
    int js[3], cs[3];
#pragma unroll
    for (int t = 0; t < 3; t++) {
        int idx = tid + t * 256;
        js[t] = idx / 12; cs[t] = idx % 12;
    }
    // pre-issue tile 0 loads
    uint4 pk[3], pv[3];
#pragma unroll
    for (int t = 0; t < 3; t++) {
        pk[t] = *(const uint4*)(Kp + (size_t)js[t] * ldk + hoff + cs[t] * 8);
        pv[t] = *(const uint4*)(Vp + (size_t)js[t] * ldv + hoff + cs[t] * 8);
    }

    for (int kt0 = 0; kt0 < Lk; kt0 += 64) {
        // ---- write staged registers to LDS (K row-major, V transposed+swz) ----
#pragma unroll
        for (int t = 0; t < 3; t++) {
            *(uint4*)&Ks[js[t] * 96 + cs[t] * 8] = pk[t];
            u16 vv[8] = {(u16)(pv[t].x & 0xffffu), (u16)(pv[t].x >> 16),
                         (u16)(pv[t].y & 0xffffu), (u16)(pv[t].y >> 16),
                         (u16)(pv[t].z & 0xffffu), (u16)(pv[t].z >> 16),
                         (u16)(pv[t].w & 0xffffu), (u16)(pv[t].w >> 16)};
            int jb = js[t] >> 3, jl = js[t] & 7;
#pragma unroll
            for (int ii = 0; ii < 8; ii++) {
                int d = cs[t] * 8 + ii;
                int sb = jb ^ (d & 7) ^ ((d >> 3) & 7);
                Vs[d * 64 + sb * 8 + jl] = vv[ii];
            }
        }
        lds_barrier();

        // ---- issue next tile's loads (in flight across the whole compute) ----
        if (kt0 + 64 < Lk) {
#pragma unroll
            for (int t = 0; t < 3; t++) {
                pk[t] = *(const uint4*)(Kp + (size_t)(kt0 + 64 + js[t]) * ldk + hoff + cs[t] * 8);
                pv[t] = *(const uint4*)(Vp + (size_t)(kt0 + 64 + js[t]) * ldv + hoff + cs[t] * 8);
            }
        }

        // ---- S = Q K^T ----
        f32x4 st[4];
        __builtin_amdgcn_s_setprio(1);
#pragma unroll
        for (int t = 0; t < 4; t++) {
            f32x4 acc = zero4;
#pragma unroll
            for (int kc = 0; kc < 3; kc++) {
                short8 kf = *(const short8*)&Ks[(t * 16 + x) * 96 + kc * 32 + g * 8];
                acc = __builtin_amdgcn_mfma_f32_16x16x32_bf16(qf[kc], kf, acc, 0, 0, 0);
            }
            st[t] = acc;
        }
        __builtin_amdgcn_s_setprio(0);

#pragma unroll
        for (int t = 0; t < 4; t++) {
            bool kv_ok = (kt0 + t * 16 + x) < el_k;
#pragma unroll
            for (int r = 0; r < 4; r++)
                st[t][r] = (kv_ok && qok[r]) ? st[t][r] * scale : NEG_MASK;
        }

        float al[4];
#pragma unroll
        for (int r = 0; r < 4; r++) {
            float rm = fmaxf(fmaxf(st[0][r], st[1][r]), fmaxf(st[2][r], st[3][r]));
            rm = fmaxf(rm, __shfl_xor(rm, 1, 64));
            rm = fmaxf(rm, __shfl_xor(rm, 2, 64));
            rm = fmaxf(rm, __shfl_xor(rm, 4, 64));
            rm = fmaxf(rm, __shfl_xor(rm, 8, 64));
            float mn = fmaxf(m[r], rm);
            al[r] = __expf(m[r] - mn);
            m[r] = mn;
            l[r] *= al[r];
        }
#pragma unroll
        for (int dt = 0; dt < 6; dt++)
#pragma unroll
            for (int r = 0; r < 4; r++) o[dt][r] *= al[r];

#pragma unroll
        for (int t = 0; t < 4; t++)
#pragma unroll
            for (int r = 0; r < 4; r++) {
                float p = __expf(st[t][r] - m[r]);
                l[r] += p;
                pw[(g * 4 + r) * 72 + t * 16 + x] = f2bf(p);
            }

        // ---- O += P V ----
        __builtin_amdgcn_s_setprio(1);
#pragma unroll
        for (int kc = 0; kc < 2; kc++) {
            short8 pf = *(const short8*)&pw[x * 72 + kc * 32 + g * 8];
#pragma unroll
            for (int dt = 0; dt < 6; dt++) {
                int d = dt * 16 + x;
                int sb = (kc * 4 + g) ^ (d & 7) ^ ((d >> 3) & 7);
                short8 vf = *(const short8*)&Vs[d * 64 + sb * 8];
                o[dt] = __builtin_amdgcn_mfma_f32_16x16x32_bf16(pf, vf, o[dt], 0, 0, 0);
            }
        }
        __builtin_amdgcn_s_setprio(0);
        lds_barrier();
    }

    float inv[4];
#pragma unroll
    for (int r = 0; r < 4; r++) {
        float lr = l[r];
        lr += __shfl_xor(lr, 1, 64);
        lr += __shfl_xor(lr, 2, 64);
        lr += __shfl_xor(lr, 4, 64);
        lr += __shfl_xor(lr, 8, 64);
        inv[r] = 1.0f / lr;
    }
#pragma unroll
    for (int dt = 0; dt < 6; dt++)
#pragma unroll
        for (int r = 0; r < 4; r++) {
            size_t ob = (size_t)(i0 + wave * 16 + g * 4 + r) * ldo + hoff + dt * 16 + x;
            AOp[ob] = f2bf(o[dt][r] * inv[r]);
        }
}

// ---------------- launcher ----------------
extern "C" void kernel_launch(void* const* d_in, const int* in_sizes, int n_in,
                              void* d_out, int out_size, void* d_ws, size_t ws_size,
                              hipStream_t stream) {
    const void* x    = d_in[0];
    const void* c    = d_in[1];
    const int* el    = (const int*)d_in[2];
    const int* us    = (const int*)d_in[3];
    const void* Wq1  = d_in[4];
    const void* Wkv1 = d_in[5];
    const void* Wo1  = d_in[6];
    const void* bo1  = d_in[7];
    const void* Wq2  = d_in[8];
    const void* Wkv2 = d_in[9];
    const void* Wo2  = d_in[10];
    const void* bo2  = d_in[11];
    const void* g1 = d_in[12]; const void* b1 = d_in[13];
    const void* g2 = d_in[14]; const void* b2 = d_in[15];
    const void* g4 = d_in[16]; const void* b4 = d_in[17];
    const void* gc = d_in[18]; const void* bc = d_in[19];
    const void* Wf1 = d_in[20]; const void* bf1 = d_in[21];
    const void* Wf2 = d_in[22]; const void* bf2 = d_in[23];

    const int B = 8, S = 512, L = 1024, C = EMBED;
    const int NX = B * L * C;
    const size_t RL = (size_t)L * C;
    const size_t RS = (size_t)S * C;

    char* ws = (char*)d_ws;
    int*  blk = (int*)ws;
    dim3 blkd(256);

    bool tierA = ws_size >= (size_t)88080448;
    bool tierB = !tierA && ws_size >= (size_t)33030208;

    detect_kernel<<<1, 64, 0, stream>>>((const u16*)x, el, us, blk);

    if (tierA) {
        // Memory map (bytes from ws):
        //   64        X   (f32, 25165824)
        //   25165888  XN  (bf16, 12582912)
        //   37748800  WT  (bf16 weight pool, 9437184)
        //   47185984  P   (37748736): Qb+KVb | CNb+KV2b+Q2b | Hh
        // total 84934720 <= 88080448
        float* X  = (float*)(ws + 64);
        u16*   XN = (u16*)(ws + 25165888);
        u16*   WT = (u16*)(ws + 37748800);
        char*  P  = ws + 47185984;
        u16* Qb   = (u16*)P;
        u16* KVb  = (u16*)(P + 12582912);
        u16* CNb  = (u16*)P;
        u16* KV2b = (u16*)(P + 6291456);
        u16* Q2b  = (u16*)(P + 18874368);
        u16* Hh   = (u16*)P;
        // WT slot offsets (u16 units)
        const size_t WTq = 0, WTkv = 589824, WTo = 1769472;
        const size_t WTf1 = 0, WTf2 = 2359296;

        wire_to_f32<<<(NX + 255) / 256, blkd, 0, stream>>>(x, 0, X, NX, blk);

        // phase-1 weight transposes
        wtrans_kernel<<<dim3(12, 12), blkd, 0, stream>>>(Wq1, 0, C, C, WT + WTq, blk);
        wtrans_kernel<<<dim3(24, 12), blkd, 0, stream>>>(Wkv1, 0, 2 * C, C, WT + WTkv, blk);
        wtrans_kernel<<<dim3(12, 12), blkd, 0, stream>>>(Wo1, 0, C, C, WT + WTo, blk);

        ln_kernel<<<B * L, blkd, 0, stream>>>(X, 0, 0, g1, b1, XN, blk);
        gemm_mfma_t<<<dim3(6, 128, 1), blkd, 0, stream>>>(XN, WT + WTq, nullptr, 0, Qb, 0, B * L, C, C, 0, 1, blk);
        gemm_mfma_t<<<dim3(12, 128, 1), blkd, 0, stream>>>(XN, WT + WTkv, nullptr, 0, KVb, 0, B * L, 2 * C, C, 0, 1, blk);
        attn_kernel<<<dim3(16, 8, 8), blkd, 0, stream>>>(Qb, KVb, KVb + C, Qb, C, 2 * C, 2 * C, C,
                                                         RL, (size_t)L * 2 * C, RL, blk, -1, L, 1);
        gemm_mfma_t<<<dim3(6, 128, 1), blkd, 0, stream>>>(Qb, WT + WTo, bo1, 0, X, 0, B * L, C, C, 1, 0, blk);

        // phase-2 weight transposes (reuse slots after Wo1 gemm)
        wtrans_kernel<<<dim3(12, 12), blkd, 0, stream>>>(Wq2, 0, C, C, WT + WTq, blk);
        wtrans_kernel<<<dim3(24, 12), blkd, 0, stream>>>(Wkv2, 0, 2 * C, C, WT + WTkv, blk);
        wtrans_kernel<<<dim3(12, 12), blkd, 0, stream>>>(Wo2, 0, C, C, WT + WTo, blk);

        ln_kernel<<<B * L, blkd, 0, stream>>>(X, 0, 0, g2, b2, XN, blk);
        ln_kernel<<<B * S, blkd, 0, stream>>>(c, 0, 2, gc, bc, CNb, blk);
        gemm_mfma_t<<<dim3(12, 64, 1), blkd, 0, stream>>>(CNb, WT + WTkv, nullptr, 0, KV2b, 0, B * S, 2 * C, C, 0, 1, blk);
        gemm_mfma_t<<<dim3(6, 128, 1), blkd, 0, stream>>>(XN, WT + WTq, nullptr, 0, Q2b, 0, B * L, C, C, 0, 1, blk);
        attn_kernel<<<dim3(16, 8, 8), blkd, 0, stream>>>(Q2b, KV2b, KV2b + C, Q2b, C, 2 * C, 2 * C, C,
                                                         RL, (size_t)S * 2 * C, RL, blk, -1, S, 0);
        gemm_mfma_t<<<dim3(6, 128, 1), blkd, 0, stream>>>(Q2b, WT + WTo, bo2, 0, X, 0, B * L, C, C, 1, 0, blk);

        // FFN weight transposes
        wtrans_kernel<<<dim3(48, 12), blkd, 0, stream>>>(Wf1, 0, 4 * C, C, WT + WTf1, blk);
        wtrans_kernel<<<dim3(12, 48), blkd, 0, stream>>>(Wf2, 0, C, 4 * C, WT + WTf2, blk);

        ln_kernel<<<B * L, blkd, 0, stream>>>(X, 0, 0, g4, b4, XN, blk);
        for (int h = 0; h < 2; h++) {
            size_t ro = (size_t)h * 4096 * C;
            gemm_mfma_t<<<dim3(24, 64, 1), blkd, 0, stream>>>(XN + ro, WT + WTf1, bf1, 0, Hh, 0, 4096, 4 * C, C, 1 | 2, 1, blk);
            gemm_mfma_t<<<dim3(6, 64, 2), blkd, 0, stream>>>(Hh, WT + WTf2, bf2, 0, X, ro, 4096, C, 4 * C, 1, 0, blk);
        }

        f32_to_out<<<(NX + 255) / 256, blkd, 0, stream>>>(X, d_out, 0, NX, blk);
    } else if (tierB) {
        float* X  = (float*)(ws + 64);
        u16*   XN = (u16*)(ws + 64 + 25165824);
        char*  P  = ws + 64 + 25165824 + 1572864;
        u16* Qb   = (u16*)P;
        u16* KVb  = (u16*)(P + 1572864);
        u16* AOb  = (u16*)(P + 4718592);
        u16* CNb  = (u16*)P;
        u16* KV2b = (u16*)(P + 786432);
        u16* Q2b  = (u16*)(P + 2359296);
        u16* AO2b = (u16*)(P + 3932160);
        u16* Hb   = (u16*)P;

        wire_to_f32<<<(NX + 255) / 256, blkd, 0, stream>>>(x, 0, X, NX, blk);

        for (int b = 0; b < B; b++) {
            size_t ro = (size_t)b * RL;
            ln_kernel<<<L, blkd, 0, stream>>>(X, ro, 0, g1, b1, XN, blk);
            gemm_mfma<<<dim3(6, 8), blkd, 0, stream>>>(XN, Wq1, 0, C, nullptr, 0, Qb, 0, L, C, C, 0, 1, blk);
            gemm_mfma<<<dim3(12, 8), blkd, 0, stream>>>(XN, Wkv1, 0, 2 * C, nullptr, 0, KVb, 0, L, 2 * C, C, 0, 1, blk);
            attn_kernel<<<dim3(16, 8), blkd, 0, stream>>>(Qb, KVb, KVb + C, AOb, C, 2 * C, 2 * C, C, 0, 0, 0, blk, b, L, 1);
            gemm_mfma<<<dim3(6, 8), blkd, 0, stream>>>(AOb, Wo1, 0, C, bo1, 0, X, ro, L, C, C, 1, 0, blk);

            ln_kernel<<<L, blkd, 0, stream>>>(X, ro, 0, g2, b2, XN, blk);
            ln_kernel<<<S, blkd, 0, stream>>>(c, (size_t)b * RS, 2, gc, bc, CNb, blk);
            gemm_mfma<<<dim3(12, 4), blkd, 0, stream>>>(CNb, Wkv2, 0, 2 * C, nullptr, 0, KV2b, 0, S, 2 * C, C, 0, 1, blk);
            gemm_mfma<<<dim3(6, 8), blkd, 0, stream>>>(XN, Wq2, 0, C, nullptr, 0, Q2b, 0, L, C, C, 0, 1, blk);
            attn_kernel<<<dim3(16, 8), blkd, 0, stream>>>(Q2b, KV2b, KV2b + C, AO2b, C, 2 * C, 2 * C, C, 0, 0, 0, blk, b, S, 0);
            gemm_mfma<<<dim3(6, 8), blkd, 0, stream>>>(AO2b, Wo2, 0, C, bo2, 0, X, ro, L, C, C, 1, 0, blk);

            ln_kernel<<<L, blkd, 0, stream>>>(X, ro, 0, g4, b4, XN, blk);
            gemm_mfma<<<dim3(24, 8), blkd, 0, stream>>>(XN, Wf1, 0, 4 * C, bf1, 0, Hb, 0, L, 4 * C, C, 1 | 2, 1, blk);
            gemm_mfma<<<dim3(6, 8), blkd, 0, stream>>>(Hb, Wf2, 0, C, bf2, 0, X, ro, L, C, 4 * C, 1, 0, blk);
        }
        f32_to_out<<<(NX + 255) / 256, blkd, 0, stream>>>(X, d_out, 0, NX, blk);
    } else {
        u16*  XN  = (u16*)(ws + 64);
        u16*  CNb = (u16*)(ws + 64 + 1572864);
        char* P2  = ws + 64 + 1572864 + 786432;
        u16* Qp  = (u16*)P2;
        u16* Kp  = (u16*)(P2 + 393216);
        u16* Vp  = (u16*)(P2 + 786432);
        u16* AOp = (u16*)(P2 + 1179648);
        u16* Hc  = (u16*)P2;

        wire_copy<<<(NX + 255) / 256, blkd, 0, stream>>>(x, d_out, NX, blk);

        for (int b = 0; b < B; b++) {
            size_t ro = (size_t)b * RL;

            ln_kernel<<<L, blkd, 0, stream>>>(d_out, ro, 2, g1, b1, XN, blk);
            for (int p = 0; p < 4; p++) {
                int h = 2 * p;
                gemm_kernel<<<dim3(3, 16), blkd, 0, stream>>>(XN, Wq1, (size_t)h * 96, C, nullptr, 0, Qp, 0, L, 192, C, 0, 1, blk);
                gemm_kernel<<<dim3(3, 16), blkd, 0, stream>>>(XN, Wkv1, (size_t)h * 96, 2 * C, nullptr, 0, Kp, 0, L, 192, C, 0, 1, blk);
                gemm_kernel<<<dim3(3, 16), blkd, 0, stream>>>(XN, Wkv1, (size_t)(C + h * 96), 2 * C, nullptr, 0, Vp, 0, L, 192, C, 0, 1, blk);
                attn_kernel<<<dim3(16, 2), blkd, 0, stream>>>(Qp, Kp, Vp, AOp, 192, 192, 192, 192, 0, 0, 0, blk, b, L, 1);
                gemm_kernel<<<dim3(12, 16), blkd, 0, stream>>>(AOp, Wo1, (size_t)h * 96 * C, C, bo1, 0, d_out, ro, L, C, 192, (p == 0) ? 1 : 0, 3, blk);
            }
            ln_kernel<<<L, blkd, 0, stream>>>(d_out, ro, 2, g2, b2, XN, blk);
            ln_kernel<<<S, blkd, 0, stream>>>(c, (size_t)b * RS, 2, gc, bc, CNb, blk);
            for (int p = 0; p < 4; p++) {
                int h = 2 * p;
                gemm_kernel<<<dim3(3, 16), blkd, 0, stream>>>(XN, Wq2, (size_t)h * 96, C, nullptr, 0, Qp, 0, L, 192, C, 0, 1, blk);
                gemm_kernel<<<dim3(3, 8), blkd, 0, stream>>>(CNb, Wkv2, (size_t)h * 96, 2 * C, nullptr, 0, Kp, 0, S, 192, C, 0, 1, blk);
                gemm_kernel<<<dim3(3, 8), blkd, 0, stream>>>(CNb, Wkv2, (size_t)(C + h * 96), 2 * C, nullptr, 0, Vp, 0, S, 192, C, 0, 1, blk);
                attn_kernel<<<dim3(16, 2), blkd, 0, stream>>>(Qp, Kp, Vp, AOp, 192, 192, 192, 192, 0, 0, 0, blk, b, S, 0);
                gemm_kernel<<<dim3(12, 16), blkd, 0, stream>>>(AOp, Wo2, (size_t)h * 96 * C, C, bo2, 0, d_out, ro, L, C, 192, (p == 0) ? 1 : 0, 3, blk);
            }
            ln_kernel<<<L, blkd, 0, stream>>>(d_out, ro, 2, g4, b4, XN, blk);
            for (int ch = 0; ch < 4; ch++) {
                gemm_kernel<<<dim3(12, 16), blkd, 0, stream>>>(XN, Wf1, (size_t)ch * C, 4 * C, bf1, ch * C, Hc, 0, L, C, C, 1 | 2, 1, blk);
                gemm_kernel<<<dim3(12, 16), blkd, 0, stream>>>(Hc, Wf2, (size_t)ch * C * C, C, bf2, 0, d_out, ro, L, C, C, (ch == 0) ? 1 : 0, 3, blk);
            }
        }
    }
}

// Round 11
// 825.004 us; speedup vs baseline: 1.0145x; 1.0145x over previous
//
#include <hip/hip_runtime.h>
#include <math.h>

#define EMBED 768
#define HEADS 8
#define HDIM  96
#define NEG_MASK (-1.0e30f)

typedef unsigned short u16;
typedef unsigned int   u32;

typedef __attribute__((ext_vector_type(4))) float f32x4;
typedef __attribute__((ext_vector_type(8))) short short8;

__device__ __forceinline__ float bf2f(u16 u) {
    return __uint_as_float(((u32)u) << 16);
}
__device__ __forceinline__ u16 f2bf(float f) {
    u32 x = __float_as_uint(f);
    u32 r = (x + 0x7fffu + ((x >> 16) & 1u)) >> 16;
    return (u16)r;
}
__device__ __forceinline__ void unpack2(u32 w, float& lo, float& hi) {
    lo = __uint_as_float(w << 16);
    hi = __uint_as_float(w & 0xffff0000u);
}
__device__ __forceinline__ float wget(const void* p, size_t i, int wf) {
    return wf ? ((const float*)p)[i] : bf2f(((const u16*)p)[i]);
}
// LDS bank swizzle: u16 offset of 8-wide k-chunk g within a 32-u16 row r.
__device__ __forceinline__ int bswz(int r, int g) {
    return ((g ^ (r & 3) ^ ((r >> 2) & 3) ^ ((r >> 4) & 3)) << 3);
}
// XOR constant of the swizzle (involution): slot g' holds chunk g'^cswz(r).
__device__ __forceinline__ int cswz(int r) {
    return (r & 3) ^ ((r >> 2) & 3) ^ ((r >> 4) & 3);
}
// Direct global->LDS DMA, 16B per lane. LDS dest = wave-uniform base +
// lane*16 (linear); swizzle is achieved by pre-swizzling the per-lane
// GLOBAL source chunk (m173 pattern).
__device__ __forceinline__ void load_lds16(const u16* g, u16* l) {
    __builtin_amdgcn_global_load_lds((const __attribute__((address_space(1))) u32*)g,
                                     (__attribute__((address_space(3))) u32*)l,
                                     16, 0, 0);
}

// ---------------- detection ----------------
__global__ __launch_bounds__(64) void detect_kernel(const u16* __restrict__ x,
                                                    const int* __restrict__ el,
                                                    const int* __restrict__ usp,
                                                    int* __restrict__ blk) {
    int lane = threadIdx.x;
    int cnt = 0;
    for (int i = lane; i < 4096; i += 64) {
        u32 e = (x[i] >> 7) & 0xFFu;
        if (e >= 0xC0u) cnt++;
    }
#pragma unroll
    for (int off = 32; off > 0; off >>= 1) cnt += __shfl_xor(cnt, off, 64);
    if (lane == 0) {
        blk[0] = (cnt > 32) ? 1 : 0;
        bool i64 = (el[1] == 0) && (el[3] == 0) && (el[5] == 0) && (el[7] == 0);
        for (int b = 0; b < 8; b++) blk[1 + b] = i64 ? el[2 * b] : el[b];
        blk[9] = usp[0];
    }
}

// ---------------- copies ----------------
__global__ void wire_to_f32(const void* __restrict__ in, size_t ioff,
                            float* __restrict__ out, int n,
                            const int* __restrict__ blk) {
    int i = blockIdx.x * blockDim.x + threadIdx.x;
    int wf = blk[0];
    if (i < n) out[i] = wget(in, ioff + (size_t)i, wf);
}
__global__ void wire_copy(const void* __restrict__ in, void* __restrict__ out,
                          int n, const int* __restrict__ blk) {
    int i = blockIdx.x * blockDim.x + threadIdx.x;
    int wf = blk[0];
    if (i < n) {
        if (wf) ((float*)out)[i] = ((const float*)in)[i];
        else    ((u16*)out)[i]   = ((const u16*)in)[i];
    }
}
__global__ void f32_to_out(const float* __restrict__ in, void* __restrict__ out,
                           size_t ooff, int n, const int* __restrict__ blk) {
    int i = blockIdx.x * blockDim.x + threadIdx.x;
    int wf = blk[0];
    if (i < n) {
        if (wf) ((float*)out)[ooff + i] = in[i];
        else    ((u16*)out)[ooff + i]   = f2bf(in[i]);
    }
}

// ---------------- weight transpose: W[K][N] (f32|bf16) -> WT[N][K] bf16 ----
__global__ __launch_bounds__(256) void wtrans_kernel(const void* __restrict__ W, size_t woff,
                                                     int ldw, int K,
                                                     u16* __restrict__ WT,
                                                     const int* __restrict__ blk) {
    __shared__ u16 T[64][65];   // T[n_local][k_local]
    int wf = blk[0];
    int n0 = blockIdx.x * 64, k0 = blockIdx.y * 64;
    int tid = threadIdx.x;
    int tr = tid >> 4, tc4 = (tid & 15) * 4;
#pragma unroll
    for (int i = 0; i < 4; i++) {
        int k = tr + i * 16;
        if (wf) {
            const float* src = (const float*)W + woff + (size_t)(k0 + k) * ldw + n0 + tc4;
            float4 f = *(const float4*)src;
            T[tc4 + 0][k] = f2bf(f.x); T[tc4 + 1][k] = f2bf(f.y);
            T[tc4 + 2][k] = f2bf(f.z); T[tc4 + 3][k] = f2bf(f.w);
        } else {
            const u16* src = (const u16*)W + woff + (size_t)(k0 + k) * ldw + n0 + tc4;
            uint2 u = *(const uint2*)src;
            T[tc4 + 0][k] = (u16)(u.x & 0xffffu); T[tc4 + 1][k] = (u16)(u.x >> 16);
            T[tc4 + 2][k] = (u16)(u.y & 0xffffu); T[tc4 + 3][k] = (u16)(u.y >> 16);
        }
    }
    __syncthreads();
#pragma unroll
    for (int i = 0; i < 4; i++) {
        int n = tr + i * 16;
        u32 w0 = (u32)T[n][tc4 + 0] | ((u32)T[n][tc4 + 1] << 16);
        u32 w1 = (u32)T[n][tc4 + 2] | ((u32)T[n][tc4 + 3] << 16);
        *(uint2*)(WT + (size_t)(n0 + n) * K + k0 + tc4) = make_uint2(w0, w1);
    }
}

// ---------------- LayerNorm ----------------
__global__ __launch_bounds__(256) void ln_kernel(const void* __restrict__ in,
                                                 size_t ioff, int sel,
                                                 const void* __restrict__ g,
                                                 const void* __restrict__ b,
                                                 u16* __restrict__ out,
                                                 const int* __restrict__ blk) {
    int wf = blk[0];
    int row = blockIdx.x, tid = threadIdx.x;
    size_t base = ioff + (size_t)row * EMBED;
    float v[3];
#pragma unroll
    for (int e = 0; e < 3; e++) {
        size_t idx = base + tid + e * 256;
        v[e] = (sel == 0) ? ((const float*)in)[idx] : wget(in, idx, wf);
    }
    float s = v[0] + v[1] + v[2];
    float q = v[0] * v[0] + v[1] * v[1] + v[2] * v[2];
#pragma unroll
    for (int off = 32; off > 0; off >>= 1) {
        s += __shfl_xor(s, off, 64);
        q += __shfl_xor(q, off, 64);
    }
    __shared__ float sb[8];
    int wid = tid >> 6, lane = tid & 63;
    if (lane == 0) { sb[wid] = s; sb[4 + wid] = q; }
    __syncthreads();
    if (tid == 0) {
        sb[0] = sb[0] + sb[1] + sb[2] + sb[3];
        sb[4] = sb[4] + sb[5] + sb[6] + sb[7];
    }
    __syncthreads();
    float mean = sb[0] * (1.0f / EMBED);
    float var  = sb[4] * (1.0f / EMBED) - mean * mean;
    float rs   = rsqrtf(var + 1e-5f);
    size_t obase = (size_t)row * EMBED;
#pragma unroll
    for (int e = 0; e < 3; e++) {
        int col = tid + e * 256;
        out[obase + col] = f2bf((v[e] - mean) * rs * wget(g, col, wf) + wget(b, col, wf));
    }
}

// ---------------- legacy VALU GEMM (tier-C fallback: handles N=192) ----------------
__global__ __launch_bounds__(256) void gemm_kernel(const u16* __restrict__ A,
                                                   const void* __restrict__ W,
                                                   size_t woff, int ldw,
                                                   const void* __restrict__ bias, int boff,
                                                   void* __restrict__ Cv, size_t coff,
                                                   int M, int N, int K, int flags,
                                                   int tcmode, const int* __restrict__ blk) {
    __shared__ float As[16][64];
    __shared__ float Bs[16][64];
    int wf = blk[0];
    int tid = threadIdx.x;
    int tx = tid & 15, ty = tid >> 4;
    int row0 = blockIdx.y * 64, col0 = blockIdx.x * 64;
    float acc[4][4] = {};
    int ar = tid >> 2, ac4 = tid & 3;
    int br = tid >> 4, bc4 = tid & 15;

    for (int kb = 0; kb < K; kb += 16) {
        {
            uint2 u = *(const uint2*)(A + (size_t)(row0 + ar) * K + kb + ac4 * 4);
            float a0, a1, a2, a3;
            unpack2(u.x, a0, a1); unpack2(u.y, a2, a3);
            As[ac4 * 4 + 0][ar] = a0; As[ac4 * 4 + 1][ar] = a1;
            As[ac4 * 4 + 2][ar] = a2; As[ac4 * 4 + 3][ar] = a3;
        }
        {
            size_t off = woff + (size_t)(kb + br) * ldw + col0 + bc4 * 4;
            if (wf) {
                float4 u = *(const float4*)((const float*)W + off);
                Bs[br][bc4 * 4 + 0] = u.x; Bs[br][bc4 * 4 + 1] = u.y;
                Bs[br][bc4 * 4 + 2] = u.z; Bs[br][bc4 * 4 + 3] = u.w;
            } else {
                uint2 u = *(const uint2*)((const u16*)W + off);
                float b0, b1, b2, b3;
                unpack2(u.x, b0, b1); unpack2(u.y, b2, b3);
                Bs[br][bc4 * 4 + 0] = b0; Bs[br][bc4 * 4 + 1] = b1;
                Bs[br][bc4 * 4 + 2] = b2; Bs[br][bc4 * 4 + 3] = b3;
            }
        }
        __syncthreads();
#pragma unroll
        for (int kk = 0; kk < 16; kk++) {
            float4 a = *(const float4*)&As[kk][ty * 4];
            float4 b = *(const float4*)&Bs[kk][tx * 4];
            float av[4] = {a.x, a.y, a.z, a.w};
            float bv[4] = {b.x, b.y, b.z, b.w};
#pragma unroll
            for (int i = 0; i < 4; i++)
#pragma unroll
                for (int j = 0; j < 4; j++)
                    acc[i][j] += av[i] * bv[j];
        }
        __syncthreads();
    }

#pragma unroll
    for (int i = 0; i < 4; i++) {
        int m = row0 + ty * 4 + i;
#pragma unroll
        for (int j = 0; j < 4; j++) {
            int n = col0 + tx * 4 + j;
            float v = acc[i][j];
            if (flags & 1) v += wget(bias, boff + n, wf);
            if (flags & 2) v = 0.5f * v * (1.0f + erff(v * 0.70710678118654752f));
            size_t idx = coff + (size_t)m * N + n;
            if (tcmode == 0) {
                ((float*)Cv)[idx] += v;
            } else if (tcmode == 1) {
                ((u16*)Cv)[idx] = f2bf(v);
            } else {
                if (wf) ((float*)Cv)[idx] += v;
                else { u16* p = (u16*)Cv; p[idx] = f2bf(v + bf2f(p[idx])); }
            }
        }
    }
}

// ---------------- MFMA GEMM (tier-B, reg-staged scatter B; legacy) ----------
__global__ __launch_bounds__(256) void gemm_mfma(const u16* __restrict__ A,
                                                 const void* __restrict__ W,
                                                 size_t woff, int ldw,
                                                 const void* __restrict__ bias, int boff,
                                                 void* __restrict__ Cv, size_t coff,
                                                 int M, int N, int K, int flags,
                                                 int tcmode, const int* __restrict__ blk) {
    __shared__ __align__(16) u16 As[128 * 32];
    __shared__ __align__(16) u16 Bs[128 * 32];
    int wf = blk[0];
    int tid = threadIdx.x;
    int wave = tid >> 6, lane = tid & 63;
    int x = lane & 15, g = lane >> 4;
    int wm = wave >> 1, wn = wave & 1;
    int row0 = blockIdx.y * 128, col0 = blockIdx.x * 128;

    int ar  = tid >> 1, ah = tid & 1;
    int bk  = tid >> 3, bn0 = (tid & 7) * 16;

    f32x4 acc[4][4];
#pragma unroll
    for (int i = 0; i < 4; i++)
#pragma unroll
        for (int j = 0; j < 4; j++) acc[i][j] = (f32x4){0.f, 0.f, 0.f, 0.f};

    for (int kb = 0; kb < K; kb += 32) {
        {
            const u16* asrc = A + (size_t)(row0 + ar) * K + kb + ah * 16;
            uint4 a0 = *(const uint4*)asrc;
            uint4 a1 = *(const uint4*)(asrc + 8);
            *(uint4*)&As[ar * 32 + bswz(ar, ah * 2 + 0)] = a0;
            *(uint4*)&As[ar * 32 + bswz(ar, ah * 2 + 1)] = a1;
        }
        {
            u16 bv[16];
            if (wf) {
                const float* wsrc = (const float*)W + woff + (size_t)(kb + bk) * ldw + col0 + bn0;
#pragma unroll
                for (int i = 0; i < 16; i += 4) {
                    float4 f = *(const float4*)(wsrc + i);
                    bv[i + 0] = f2bf(f.x); bv[i + 1] = f2bf(f.y);
                    bv[i + 2] = f2bf(f.z); bv[i + 3] = f2bf(f.w);
                }
            } else {
                const u16* wsrc = (const u16*)W + woff + (size_t)(kb + bk) * ldw + col0 + bn0;
                ((uint4*)bv)[0] = *(const uint4*)wsrc;
                ((uint4*)bv)[1] = *(const uint4*)(wsrc + 8);
            }
            int kg = bk >> 3, kl = bk & 7;
#pragma unroll
            for (int i = 0; i < 16; i++)
                Bs[(bn0 + i) * 32 + bswz(bn0 + i, kg) + kl] = bv[i];
        }
        __syncthreads();

        short8 af[4], bf[4];
#pragma unroll
        for (int mt = 0; mt < 4; mt++) {
            int r = wm * 64 + mt * 16 + x;
            af[mt] = *(const short8*)&As[r * 32 + bswz(r, g)];
        }
#pragma unroll
        for (int nt = 0; nt < 4; nt++) {
            int n = wn * 64 + nt * 16 + x;
            bf[nt] = *(const short8*)&Bs[n * 32 + bswz(n, g)];
        }
#pragma unroll
        for (int mt = 0; mt < 4; mt++)
#pragma unroll
            for (int nt = 0; nt < 4; nt++)
                acc[mt][nt] = __builtin_amdgcn_mfma_f32_16x16x32_bf16(af[mt], bf[nt], acc[mt][nt], 0, 0, 0);
        __syncthreads();
    }

#pragma unroll
    for (int mt = 0; mt < 4; mt++) {
#pragma unroll
        for (int nt = 0; nt < 4; nt++) {
#pragma unroll
            for (int r = 0; r < 4; r++) {
                int m = row0 + wm * 64 + mt * 16 + g * 4 + r;
                int n = col0 + wn * 64 + nt * 16 + x;
                float v = acc[mt][nt][r];
                if (flags & 1) v += wget(bias, boff + n, wf);
                if (flags & 2) v = 0.5f * v * (1.0f + erff(v * 0.70710678118654752f));
                size_t idx = coff + (size_t)m * N + n;
                if (tcmode == 0) {
                    ((float*)Cv)[idx] += v;
                } else if (tcmode == 1) {
                    ((u16*)Cv)[idx] = f2bf(v);
                } else {
                    if (wf) ((float*)Cv)[idx] += v;
                    else { u16* p = (u16*)Cv; p[idx] = f2bf(v + bf2f(p[idx])); }
                }
            }
        }
    }
}

// ---------------- MFMA GEMM v5: 64x128 tile, pre-transposed bf16 weights,
// global_load_lds staging (direct HBM->LDS DMA, no VGPR round trip).
// LDS destination is LINEAR (wave-uniform base + lane*16, HW requirement);
// the bank swizzle is realized by XORing the per-lane GLOBAL k-chunk index
// with cswz(row) (involution), so bswz-swizzled b128 fragment reads return
// the correct data. Double-buffered; next-tile loads issue before the MFMA
// cluster; the single __syncthreads per K-step drains vmcnt (required: loads
// are LDS-bound) after compute has covered most of their latency.
// Optional split-K via gridDim.z (atomic f32; bias applied by z==0 only).
__global__ __launch_bounds__(256) void gemm_mfma_t(const u16* __restrict__ A,
                                                   const u16* __restrict__ BT,
                                                   const void* __restrict__ bias, int boff,
                                                   void* __restrict__ Cv, size_t coff,
                                                   int M, int N, int K, int flags,
                                                   int tcmode, const int* __restrict__ blk) {
    __shared__ __align__(16) u16 As[2][64 * 32];
    __shared__ __align__(16) u16 Bs[2][128 * 32];
    int wf = blk[0];
    int tid = threadIdx.x;
    int wave = tid >> 6, lane = tid & 63;
    int x = lane & 15, g = lane >> 4;
    int wm = wave >> 1, wn = wave & 1;
    int row0 = blockIdx.y * 64, col0 = blockIdx.x * 128;
    int KS = gridDim.z, kz = blockIdx.z;
    int Kc = K / KS;

    // staging geometry: lane covers (row = wave*16 + lane/4, slot = lane&3)
    int l4 = lane >> 2, lg = lane & 3;
    int arow = wave * 16 + l4;
    int brow0 = arow;            // B rows 0..63
    int brow1 = 64 + arow;       // B rows 64..127
    const u16* agp  = A  + (size_t)(row0 + arow) * K + kz * Kc + (lg ^ cswz(arow))  * 8;
    const u16* bgp0 = BT + (size_t)(col0 + brow0) * K + kz * Kc + (lg ^ cswz(brow0)) * 8;
    const u16* bgp1 = BT + (size_t)(col0 + brow1) * K + kz * Kc + (lg ^ cswz(brow1)) * 8;

    int ra[2], rb[4];
#pragma unroll
    for (int mt = 0; mt < 2; mt++) {
        int r = wm * 32 + mt * 16 + x;
        ra[mt] = r * 32 + bswz(r, g);
    }
#pragma unroll
    for (int nt = 0; nt < 4; nt++) {
        int n = wn * 64 + nt * 16 + x;
        rb[nt] = n * 32 + bswz(n, g);
    }

    f32x4 acc[2][4];
#pragma unroll
    for (int i = 0; i < 2; i++)
#pragma unroll
        for (int j = 0; j < 4; j++) acc[i][j] = (f32x4){0.f, 0.f, 0.f, 0.f};

    int nsteps = Kc >> 5;

    // prologue: tile 0 -> buffer 0
    load_lds16(agp,  &As[0][wave * 512]);
    load_lds16(bgp0, &Bs[0][wave * 512]);
    load_lds16(bgp1, &Bs[0][2048 + wave * 512]);
    __syncthreads();

    int cur = 0;
    for (int s = 0; s < nsteps; ++s) {
        bool nxt = (s + 1 < nsteps);
        if (nxt) {
            agp += 32; bgp0 += 32; bgp1 += 32;
            load_lds16(agp,  &As[cur ^ 1][wave * 512]);
            load_lds16(bgp0, &Bs[cur ^ 1][wave * 512]);
            load_lds16(bgp1, &Bs[cur ^ 1][2048 + wave * 512]);
        }
        short8 af[2], bfr[4];
#pragma unroll
        for (int mt = 0; mt < 2; mt++) af[mt] = *(const short8*)&As[cur][ra[mt]];
#pragma unroll
        for (int nt = 0; nt < 4; nt++) bfr[nt] = *(const short8*)&Bs[cur][rb[nt]];
#pragma unroll
        for (int mt = 0; mt < 2; mt++)
#pragma unroll
            for (int nt = 0; nt < 4; nt++)
                acc[mt][nt] = __builtin_amdgcn_mfma_f32_16x16x32_bf16(af[mt], bfr[nt], acc[mt][nt], 0, 0, 0);
        if (nxt) {
            __syncthreads();   // drains vmcnt -> next buffer fully landed
            cur ^= 1;
        }
    }

    bool kz0 = (kz == 0);
#pragma unroll
    for (int mt = 0; mt < 2; mt++) {
#pragma unroll
        for (int nt = 0; nt < 4; nt++) {
#pragma unroll
            for (int r = 0; r < 4; r++) {
                int m = row0 + wm * 32 + mt * 16 + g * 4 + r;
                int n = col0 + wn * 64 + nt * 16 + x;
                float v = acc[mt][nt][r];
                if ((flags & 1) && kz0) v += wget(bias, boff + n, wf);
                if (flags & 2) v = 0.5f * v * (1.0f + erff(v * 0.70710678118654752f));
                size_t idx = coff + (size_t)m * N + n;
                if (tcmode == 0) {
                    if (KS > 1) atomicAdd(&((float*)Cv)[idx], v);
                    else        ((float*)Cv)[idx] += v;
                } else if (tcmode == 1) {
                    ((u16*)Cv)[idx] = f2bf(v);
                } else {
                    if (wf) ((float*)Cv)[idx] += v;
                    else { u16* p = (u16*)Cv; p[idx] = f2bf(v + bf2f(p[idx])); }
                }
            }
        }
    }
}

// ---------------- flash attention (bf16 MFMA) ----------------
// EXACT round-6 body (measured 94.4 us): plain staging, __syncthreads, no
// el-skip (load imbalance > savings), no T14 (register spill: +25MB scratch
// writes), no setprio. In-place safe (AO == Q).
__global__ __launch_bounds__(256) void attn_kernel(const u16* __restrict__ Q,
                                                   const u16* __restrict__ K,
                                                   const u16* __restrict__ V,
                                                   u16* __restrict__ AO,
                                                   int ldq, int ldk, int ldv, int ldo,
                                                   size_t qss, size_t kss, size_t oss,
                                                   const int* __restrict__ blk,
                                                   int bfix, int Lk, int is_self) {
    int bz   = (bfix < 0) ? blockIdx.z : 0;
    int bidx = (bfix < 0) ? blockIdx.z : bfix;
    const u16* Qp = Q + (size_t)bz * qss;
    const u16* Kp = K + (size_t)bz * kss;
    const u16* Vp = V + (size_t)bz * kss;
    u16* AOp = AO + (size_t)bz * oss;

    int hoff = blockIdx.y * HDIM;
    int i0 = blockIdx.x * 64;
    int tid = threadIdx.x;
    int wave = tid >> 6, lane = tid & 63;
    int x = lane & 15, g = lane >> 4;

    int elb = blk[1 + bidx];
    int el_q = elb * blk[9];
    int el_k = is_self ? el_q : elb;

    __shared__ __align__(16) u16 Ks[64 * 96];
    __shared__ __align__(16) u16 Vs[96 * 64];
    __shared__ __align__(16) u16 Ps[4][16 * 72];

    short8 qf[3];
    {
        const u16* qrow = Qp + (size_t)(i0 + wave * 16 + x) * ldq + hoff;
#pragma unroll
        for (int kc = 0; kc < 3; kc++)
            qf[kc] = *(const short8*)(qrow + kc * 32 + g * 8);
    }

    const f32x4 zero4 = {0.f, 0.f, 0.f, 0.f};
    f32x4 o[6];
#pragma unroll
    for (int dt = 0; dt < 6; dt++) o[dt] = zero4;
    float m[4], l[4];
#pragma unroll
    for (int r = 0; r < 4; r++) { m[r] = NEG_MASK; l[r] = 0.f; }

    bool qok[4];
#pragma unroll
    for (int r = 0; r < 4; r++) qok[r] = (i0 + wave * 16 + g * 4 + r) < el_q;

    const float scale = 0.10206207261596576f;  // 1/sqrt(96)
    u16* pw = &Ps[wave][0];

    for (int kt0 = 0; kt0 < Lk; kt0 += 64) {
#pragma unroll
        for (int t = 0; t < 3; t++) {
            int idx = tid + t * 256;
            int j = idx / 12, c = idx % 12;
            *(uint4*)&Ks[j * 96 + c * 8] =
                *(const uint4*)(Kp + (size_t)(kt0 + j) * ldk + hoff + c * 8);
            uint4 vu = *(const uint4*)(Vp + (size_t)(kt0 + j) * ldv + hoff + c * 8);
            u16 vv[8] = {(u16)(vu.x & 0xffffu), (u16)(vu.x >> 16),
                         (u16)(vu.y & 0xffffu), (u16)(vu.y >> 16),
                         (u16)(vu.z & 0xffffu), (u16)(vu.z >> 16),
                         (u16)(vu.w & 0xffffu), (u16)(vu.w >> 16)};
            int jb = j >> 3, jl = j & 7;
#pragma unroll
            for (int ii = 0; ii < 8; ii++) {
                int d = c * 8 + ii;
                int sb = jb ^ (d & 7) ^ ((d >> 3) & 7);
                Vs[d * 64 + sb * 8 + jl] = vv[ii];
            }
        }
        __syncthreads();

        f32x4 st[4];
#pragma unroll
        for (int t = 0; t < 4; t++) {
            f32x4 acc = zero4;
#pragma unroll
            for (int kc = 0; kc < 3; kc++) {
                short8 kf = *(const short8*)&Ks[(t * 16 + x) * 96 + kc * 32 + g * 8];
                acc = __builtin_amdgcn_mfma_f32_16x16x32_bf16(qf[kc], kf, acc, 0, 0, 0);
            }
            st[t] = acc;
        }

#pragma unroll
        for (int t = 0; t < 4; t++) {
            bool kv_ok = (kt0 + t * 16 + x) < el_k;
#pragma unroll
            for (int r = 0; r < 4; r++)
                st[t][r] = (kv_ok && qok[r]) ? st[t][r] * scale : NEG_MASK;
        }

        float al[4];
#pragma unroll
        for (int r = 0; r < 4; r++) {
            float rm = fmaxf(fmaxf(st[0][r], st[1][r]), fmaxf(st[2][r], st[3][r]));
            rm = fmaxf(rm, __shfl_xor(rm, 1, 64));
            rm = fmaxf(rm, __shfl_xor(rm, 2, 64));
            rm = fmaxf(rm, __shfl_xor(rm, 4, 64));
            rm = fmaxf(rm, __shfl_xor(rm, 8, 64));
            float mn = fmaxf(m[r], rm);
            al[r] = __expf(m[r] - mn);
            m[r] = mn;
            l[r] *= al[r];
        }
#pragma unroll
        for (int dt = 0; dt < 6; dt++)
#pragma unroll
            for (int r = 0; r < 4; r++) o[dt][r] *= al[r];

#pragma unroll
        for (int t = 0; t < 4; t++)
#pragma unroll
            for (int r = 0; r < 4; r++) {
                float p = __expf(st[t][r] - m[r]);
                l[r] += p;
                pw[(g * 4 + r) * 72 + t * 16 + x] = f2bf(p);
            }

#pragma unroll
        for (int kc = 0; kc < 2; kc++) {
            short8 pf = *(const short8*)&pw[x * 72 + kc * 32 + g * 8];
#pragma unroll
            for (int dt = 0; dt < 6; dt++) {
                int d = dt * 16 + x;
                int sb = (kc * 4 + g) ^ (d & 7) ^ ((d >> 3) & 7);
                short8 vf = *(const short8*)&Vs[d * 64 + sb * 8];
                o[dt] = __builtin_amdgcn_mfma_f32_16x16x32_bf16(pf, vf, o[dt], 0, 0, 0);
            }
        }
        __syncthreads();
    }

    float inv[4];
#pragma unroll
    for (int r = 0; r < 4; r++) {
        float lr = l[r];
        lr += __shfl_xor(lr, 1, 64);
        lr += __shfl_xor(lr, 2, 64);
        lr += __shfl_xor(lr, 4, 64);
        lr += __shfl_xor(lr, 8, 64);
        inv[r] = 1.0f / lr;
    }
#pragma unroll
    for (int dt = 0; dt < 6; dt++)
#pragma unroll
        for (int r = 0; r < 4; r++) {
            size_t ob = (size_t)(i0 + wave * 16 + g * 4 + r) * ldo + hoff + dt * 16 + x;
            AOp[ob] = f2bf(o[dt][r] * inv[r]);
        }
}

// ---------------- launcher ----------------
extern "C" void kernel_launch(void* const* d_in, const int* in_sizes, int n_in,
                              void* d_out, int out_size, void* d_ws, size_t ws_size,
                              hipStream_t stream) {
    const void* x    = d_in[0];
    const void* c    = d_in[1];
    const int* el    = (const int*)d_in[2];
    const int* us    = (const int*)d_in[3];
    const void* Wq1  = d_in[4];
    const void* Wkv1 = d_in[5];
    const void* Wo1  = d_in[6];
    const void* bo1  = d_in[7];
    const void* Wq2  = d_in[8];
    const void* Wkv2 = d_in[9];
    const void* Wo2  = d_in[10];
    const void* bo2  = d_in[11];
    const void* g1 = d_in[12]; const void* b1 = d_in[13];
    const void* g2 = d_in[14]; const void* b2 = d_in[15];
    const void* g4 = d_in[16]; const void* b4 = d_in[17];
    const void* gc = d_in[18]; const void* bc = d_in[19];
    const void* Wf1 = d_in[20]; const void* bf1 = d_in[21];
    const void* Wf2 = d_in[22]; const void* bf2 = d_in[23];

    const int B = 8, S = 512, L = 1024, C = EMBED;
    const int NX = B * L * C;
    const size_t RL = (size_t)L * C;
    const size_t RS = (size_t)S * C;

    char* ws = (char*)d_ws;
    int*  blk = (int*)ws;
    dim3 blkd(256);

    bool tierA = ws_size >= (size_t)88080448;
    bool tierB = !tierA && ws_size >= (size_t)33030208;

    detect_kernel<<<1, 64, 0, stream>>>((const u16*)x, el, us, blk);

    if (tierA) {
        // Memory map (bytes from ws):
        //   64        X   (f32, 25165824)
        //   25165888  XN  (bf16, 12582912)
        //   37748800  WT  (bf16 weight pool, 9437184)
        //   47185984  P   (37748736): Qb+KVb | CNb+KV2b+Q2b | Hh
        // total 84934720 <= 88080448
        float* X  = (float*)(ws + 64);
        u16*   XN = (u16*)(ws + 25165888);
        u16*   WT = (u16*)(ws + 37748800);
        char*  P  = ws + 47185984;
        u16* Qb   = (u16*)P;
        u16* KVb  = (u16*)(P + 12582912);
        u16* CNb  = (u16*)P;
        u16* KV2b = (u16*)(P + 6291456);
        u16* Q2b  = (u16*)(P + 18874368);
        u16* Hh   = (u16*)P;
        // WT slot offsets (u16 units)
        const size_t WTq = 0, WTkv = 589824, WTo = 1769472;
        const size_t WTf1 = 0, WTf2 = 2359296;

        wire_to_f32<<<(NX + 255) / 256, blkd, 0, stream>>>(x, 0, X, NX, blk);

        // phase-1 weight transposes
        wtrans_kernel<<<dim3(12, 12), blkd, 0, stream>>>(Wq1, 0, C, C, WT + WTq, blk);
        wtrans_kernel<<<dim3(24, 12), blkd, 0, stream>>>(Wkv1, 0, 2 * C, C, WT + WTkv, blk);
        wtrans_kernel<<<dim3(12, 12), blkd, 0, stream>>>(Wo1, 0, C, C, WT + WTo, blk);

        ln_kernel<<<B * L, blkd, 0, stream>>>(X, 0, 0, g1, b1, XN, blk);
        gemm_mfma_t<<<dim3(6, 128, 1), blkd, 0, stream>>>(XN, WT + WTq, nullptr, 0, Qb, 0, B * L, C, C, 0, 1, blk);
        gemm_mfma_t<<<dim3(12, 128, 1), blkd, 0, stream>>>(XN, WT + WTkv, nullptr, 0, KVb, 0, B * L, 2 * C, C, 0, 1, blk);
        attn_kernel<<<dim3(16, 8, 8), blkd, 0, stream>>>(Qb, KVb, KVb + C, Qb, C, 2 * C, 2 * C, C,
                                                         RL, (size_t)L * 2 * C, RL, blk, -1, L, 1);
        gemm_mfma_t<<<dim3(6, 128, 1), blkd, 0, stream>>>(Qb, WT + WTo, bo1, 0, X, 0, B * L, C, C, 1, 0, blk);

        // phase-2 weight transposes (reuse slots after Wo1 gemm)
        wtrans_kernel<<<dim3(12, 12), blkd, 0, stream>>>(Wq2, 0, C, C, WT + WTq, blk);
        wtrans_kernel<<<dim3(24, 12), blkd, 0, stream>>>(Wkv2, 0, 2 * C, C, WT + WTkv, blk);
        wtrans_kernel<<<dim3(12, 12), blkd, 0, stream>>>(Wo2, 0, C, C, WT + WTo, blk);

        ln_kernel<<<B * L, blkd, 0, stream>>>(X, 0, 0, g2, b2, XN, blk);
        ln_kernel<<<B * S, blkd, 0, stream>>>(c, 0, 2, gc, bc, CNb, blk);
        gemm_mfma_t<<<dim3(12, 64, 1), blkd, 0, stream>>>(CNb, WT + WTkv, nullptr, 0, KV2b, 0, B * S, 2 * C, C, 0, 1, blk);
        gemm_mfma_t<<<dim3(6, 128, 1), blkd, 0, stream>>>(XN, WT + WTq, nullptr, 0, Q2b, 0, B * L, C, C, 0, 1, blk);
        attn_kernel<<<dim3(16, 8, 8), blkd, 0, stream>>>(Q2b, KV2b, KV2b + C, Q2b, C, 2 * C, 2 * C, C,
                                                         RL, (size_t)S * 2 * C, RL, blk, -1, S, 0);
        gemm_mfma_t<<<dim3(6, 128, 1), blkd, 0, stream>>>(Q2b, WT + WTo, bo2, 0, X, 0, B * L, C, C, 1, 0, blk);

        // FFN weight transposes
        wtrans_kernel<<<dim3(48, 12), blkd, 0, stream>>>(Wf1, 0, 4 * C, C, WT + WTf1, blk);
        wtrans_kernel<<<dim3(12, 48), blkd, 0, stream>>>(Wf2, 0, C, 4 * C, WT + WTf2, blk);

        ln_kernel<<<B * L, blkd, 0, stream>>>(X, 0, 0, g4, b4, XN, blk);
        for (int h = 0; h < 2; h++) {
            size_t ro = (size_t)h * 4096 * C;
            gemm_mfma_t<<<dim3(24, 64, 1), blkd, 0, stream>>>(XN + ro, WT + WTf1, bf1, 0, Hh, 0, 4096, 4 * C, C, 1 | 2, 1, blk);
            gemm_mfma_t<<<dim3(6, 64, 2), blkd, 0, stream>>>(Hh, WT + WTf2, bf2, 0, X, ro, 4096, C, 4 * C, 1, 0, blk);
        }

        f32_to_out<<<(NX + 255) / 256, blkd, 0, stream>>>(X, d_out, 0, NX, blk);
    } else if (tierB) {
        float* X  = (float*)(ws + 64);
        u16*   XN = (u16*)(ws + 64 + 25165824);
        char*  P  = ws + 64 + 25165824 + 1572864;
        u16* Qb   = (u16*)P;
        u16* KVb  = (u16*)(P + 1572864);
        u16* AOb  = (u16*)(P + 4718592);
        u16* CNb  = (u16*)P;
        u16* KV2b = (u16*)(P + 786432);
        u16* Q2b  = (u16*)(P + 2359296);
        u16* AO2b = (u16*)(P + 3932160);
        u16* Hb   = (u16*)P;

        wire_to_f32<<<(NX + 255) / 256, blkd, 0, stream>>>(x, 0, X, NX, blk);

        for (int b = 0; b < B; b++) {
            size_t ro = (size_t)b * RL;
            ln_kernel<<<L, blkd, 0, stream>>>(X, ro, 0, g1, b1, XN, blk);
            gemm_mfma<<<dim3(6, 8), blkd, 0, stream>>>(XN, Wq1, 0, C, nullptr, 0, Qb, 0, L, C, C, 0, 1, blk);
            gemm_mfma<<<dim3(12, 8), blkd, 0, stream>>>(XN, Wkv1, 0, 2 * C, nullptr, 0, KVb, 0, L, 2 * C, C, 0, 1, blk);
            attn_kernel<<<dim3(16, 8), blkd, 0, stream>>>(Qb, KVb, KVb + C, AOb, C, 2 * C, 2 * C, C, 0, 0, 0, blk, b, L, 1);
            gemm_mfma<<<dim3(6, 8), blkd, 0, stream>>>(AOb, Wo1, 0, C, bo1, 0, X, ro, L, C, C, 1, 0, blk);

            ln_kernel<<<L, blkd, 0, stream>>>(X, ro, 0, g2, b2, XN, blk);
            ln_kernel<<<S, blkd, 0, stream>>>(c, (size_t)b * RS, 2, gc, bc, CNb, blk);
            gemm_mfma<<<dim3(12, 4), blkd, 0, stream>>>(CNb, Wkv2, 0, 2 * C, nullptr, 0, KV2b, 0, S, 2 * C, C, 0, 1, blk);
            gemm_mfma<<<dim3(6, 8), blkd, 0, stream>>>(XN, Wq2, 0, C, nullptr, 0, Q2b, 0, L, C, C, 0, 1, blk);
            attn_kernel<<<dim3(16, 8), blkd, 0, stream>>>(Q2b, KV2b, KV2b + C, AO2b, C, 2 * C, 2 * C, C, 0, 0, 0, blk, b, S, 0);
            gemm_mfma<<<dim3(6, 8), blkd, 0, stream>>>(AO2b, Wo2, 0, C, bo2, 0, X, ro, L, C, C, 1, 0, blk);

            ln_kernel<<<L, blkd, 0, stream>>>(X, ro, 0, g4, b4, XN, blk);
            gemm_mfma<<<dim3(24, 8), blkd, 0, stream>>>(XN, Wf1, 0, 4 * C, bf1, 0, Hb, 0, L, 4 * C, C, 1 | 2, 1, blk);
            gemm_mfma<<<dim3(6, 8), blkd, 0, stream>>>(Hb, Wf2, 0, C, bf2, 0, X, ro, L, C, 4 * C, 1, 0, blk);
        }
        f32_to_out<<<(NX + 255) / 256, blkd, 0, stream>>>(X, d_out, 0, NX, blk);
    } else {
        u16*  XN  = (u16*)(ws + 64);
        u16*  CNb = (u16*)(ws + 64 + 1572864);
        char* P2  = ws + 64 + 1572864 + 786432;
        u16* Qp  = (u16*)P2;
        u16* Kp  = (u16*)(P2 + 393216);
        u16* Vp  = (u16*)(P2 + 786432);
        u16* AOp = (u16*)(P2 + 1179648);
        u16* Hc  = (u16*)P2;

        wire_copy<<<(NX + 255) / 256, blkd, 0, stream>>>(x, d_out, NX, blk);

        for (int b = 0; b < B; b++) {
            size_t ro = (size_t)b * RL;

            ln_kernel<<<L, blkd, 0, stream>>>(d_out, ro, 2, g1, b1, XN, blk);
            for (int p = 0; p < 4; p++) {
                int h = 2 * p;
                gemm_kernel<<<dim3(3, 16), blkd, 0, stream>>>(XN, Wq1, (size_t)h * 96, C, nullptr, 0, Qp, 0, L, 192, C, 0, 1, blk);
                gemm_kernel<<<dim3(3, 16), blkd, 0, stream>>>(XN, Wkv1, (size_t)h * 96, 2 * C, nullptr, 0, Kp, 0, L, 192, C, 0, 1, blk);
                gemm_kernel<<<dim3(3, 16), blkd, 0, stream>>>(XN, Wkv1, (size_t)(C + h * 96), 2 * C, nullptr, 0, Vp, 0, L, 192, C, 0, 1, blk);
                attn_kernel<<<dim3(16, 2), blkd, 0, stream>>>(Qp, Kp, Vp, AOp, 192, 192, 192, 192, 0, 0, 0, blk, b, L, 1);
                gemm_kernel<<<dim3(12, 16), blkd, 0, stream>>>(AOp, Wo1, (size_t)h * 96 * C, C, bo1, 0, d_out, ro, L, C, 192, (p == 0) ? 1 : 0, 3, blk);
            }
            ln_kernel<<<L, blkd, 0, stream>>>(d_out, ro, 2, g2, b2, XN, blk);
            ln_kernel<<<S, blkd, 0, stream>>>(c, (size_t)b * RS, 2, gc, bc, CNb, blk);
            for (int p = 0; p < 4; p++) {
                int h = 2 * p;
                gemm_kernel<<<dim3(3, 16), blkd, 0, stream>>>(XN, Wq2, (size_t)h * 96, C, nullptr, 0, Qp, 0, L, 192, C, 0, 1, blk);
                gemm_kernel<<<dim3(3, 8), blkd, 0, stream>>>(CNb, Wkv2, (size_t)h * 96, 2 * C, nullptr, 0, Kp, 0, S, 192, C, 0, 1, blk);
                gemm_kernel<<<dim3(3, 8), blkd, 0, stream>>>(CNb, Wkv2, (size_t)(C + h * 96), 2 * C, nullptr, 0, Vp, 0, S, 192, C, 0, 1, blk);
                attn_kernel<<<dim3(16, 2), blkd, 0, stream>>>(Qp, Kp, Vp, AOp, 192, 192, 192, 192, 0, 0, 0, blk, b, S, 0);
                gemm_kernel<<<dim3(12, 16), blkd, 0, stream>>>(AOp, Wo2, (size_t)h * 96 * C, C, bo2, 0, d_out, ro, L, C, 192, (p == 0) ? 1 : 0, 3, blk);
            }
            ln_kernel<<<L, blkd, 0, stream>>>(d_out, ro, 2, g4, b4, XN, blk);
            for (int ch = 0; ch < 4; ch++) {
                gemm_kernel<<<dim3(12, 16), blkd, 0, stream>>>(XN, Wf1, (size_t)ch * C, 4 * C, bf1, ch * C, Hc, 0, L, C, C, 1 | 2, 1, blk);
                gemm_kernel<<<dim3(12, 16), blkd, 0, stream>>>(Hc, Wf2, (size_t)ch * C * C, C, bf2, 0, d_out, ro, L, C, C, (ch == 0) ? 1 : 0, 3, blk);
            }
        }
    }
}

// Round 12
// 797.146 us; speedup vs baseline: 1.0499x; 1.0349x over previous
//
#include <hip/hip_runtime.h>
#include <math.h>

#define EMBED 768
#define HEADS 8
#define HDIM  96
#define NEG_MASK (-1.0e30f)

typedef unsigned short u16;
typedef unsigned int   u32;

typedef __attribute__((ext_vector_type(4))) float f32x4;
typedef __attribute__((ext_vector_type(8))) short short8;

__device__ __forceinline__ float bf2f(u16 u) {
    return __uint_as_float(((u32)u) << 16);
}
__device__ __forceinline__ u16 f2bf(float f) {
    u32 x = __float_as_uint(f);
    u32 r = (x + 0x7fffu + ((x >> 16) & 1u)) >> 16;
    return (u16)r;
}
__device__ __forceinline__ void unpack2(u32 w, float& lo, float& hi) {
    lo = __uint_as_float(w << 16);
    hi = __uint_as_float(w & 0xffff0000u);
}
__device__ __forceinline__ float wget(const void* p, size_t i, int wf) {
    return wf ? ((const float*)p)[i] : bf2f(((const u16*)p)[i]);
}
// LDS bank swizzle: u16 offset of 8-wide k-chunk g within a 32-u16 row r.
__device__ __forceinline__ int bswz(int r, int g) {
    return ((g ^ (r & 3) ^ ((r >> 2) & 3) ^ ((r >> 4) & 3)) << 3);
}
// XOR constant of the swizzle (involution): slot g' holds chunk g'^cswz(r).
__device__ __forceinline__ int cswz(int r) {
    return (r & 3) ^ ((r >> 2) & 3) ^ ((r >> 4) & 3);
}
// Direct global->LDS DMA, 16B per lane. LDS dest = wave-uniform base +
// lane*16 (linear); swizzle via pre-swizzled per-lane GLOBAL source chunk.
__device__ __forceinline__ void load_lds16(const u16* g, u16* l) {
    __builtin_amdgcn_global_load_lds((const __attribute__((address_space(1))) u32*)g,
                                     (__attribute__((address_space(3))) u32*)l,
                                     16, 0, 0);
}
// T1 XCD-aware chunked block remap: HW assigns XCD = linear_id % 8 (round
// robin); remapping work so each XCD owns a CONTIGUOUS chunk makes blocks
// sharing operand panels co-resident in one XCD's private L2. Bijective when
// nwg % 8 == 0 (all tier-A grids); identity fallback otherwise. Perf-only.
__device__ __forceinline__ void xcd_swz3(int& bx, int& by, int& bz) {
    int gx = gridDim.x, gy = gridDim.y;
    int nwg = gx * gy * gridDim.z;
    int lin = blockIdx.x + gx * (blockIdx.y + gy * blockIdx.z);
    if (nwg & 7) { bx = blockIdx.x; by = blockIdx.y; bz = blockIdx.z; return; }
    int wid = (lin & 7) * (nwg >> 3) + (lin >> 3);
    bx = wid % gx;
    int r = wid / gx;
    by = r % gy;
    bz = r / gy;
}

// ---------------- detection ----------------
__global__ __launch_bounds__(64) void detect_kernel(const u16* __restrict__ x,
                                                    const int* __restrict__ el,
                                                    const int* __restrict__ usp,
                                                    int* __restrict__ blk) {
    int lane = threadIdx.x;
    int cnt = 0;
    for (int i = lane; i < 4096; i += 64) {
        u32 e = (x[i] >> 7) & 0xFFu;
        if (e >= 0xC0u) cnt++;
    }
#pragma unroll
    for (int off = 32; off > 0; off >>= 1) cnt += __shfl_xor(cnt, off, 64);
    if (lane == 0) {
        blk[0] = (cnt > 32) ? 1 : 0;
        bool i64 = (el[1] == 0) && (el[3] == 0) && (el[5] == 0) && (el[7] == 0);
        for (int b = 0; b < 8; b++) blk[1 + b] = i64 ? el[2 * b] : el[b];
        blk[9] = usp[0];
    }
}

// ---------------- copies ----------------
__global__ void wire_to_f32(const void* __restrict__ in, size_t ioff,
                            float* __restrict__ out, int n,
                            const int* __restrict__ blk) {
    int i = blockIdx.x * blockDim.x + threadIdx.x;
    int wf = blk[0];
    if (i < n) out[i] = wget(in, ioff + (size_t)i, wf);
}
__global__ void wire_copy(const void* __restrict__ in, void* __restrict__ out,
                          int n, const int* __restrict__ blk) {
    int i = blockIdx.x * blockDim.x + threadIdx.x;
    int wf = blk[0];
    if (i < n) {
        if (wf) ((float*)out)[i] = ((const float*)in)[i];
        else    ((u16*)out)[i]   = ((const u16*)in)[i];
    }
}
__global__ void f32_to_out(const float* __restrict__ in, void* __restrict__ out,
                           size_t ooff, int n, const int* __restrict__ blk) {
    int i = blockIdx.x * blockDim.x + threadIdx.x;
    int wf = blk[0];
    if (i < n) {
        if (wf) ((float*)out)[ooff + i] = in[i];
        else    ((u16*)out)[ooff + i]   = f2bf(in[i]);
    }
}

// ---------------- weight transpose: W[K][N] (f32|bf16) -> WT[N][K] bf16 ----
__global__ __launch_bounds__(256) void wtrans_kernel(const void* __restrict__ W, size_t woff,
                                                     int ldw, int K,
                                                     u16* __restrict__ WT,
                                                     const int* __restrict__ blk) {
    __shared__ u16 T[64][65];   // T[n_local][k_local]
    int wf = blk[0];
    int n0 = blockIdx.x * 64, k0 = blockIdx.y * 64;
    int tid = threadIdx.x;
    int tr = tid >> 4, tc4 = (tid & 15) * 4;
#pragma unroll
    for (int i = 0; i < 4; i++) {
        int k = tr + i * 16;
        if (wf) {
            const float* src = (const float*)W + woff + (size_t)(k0 + k) * ldw + n0 + tc4;
            float4 f = *(const float4*)src;
            T[tc4 + 0][k] = f2bf(f.x); T[tc4 + 1][k] = f2bf(f.y);
            T[tc4 + 2][k] = f2bf(f.z); T[tc4 + 3][k] = f2bf(f.w);
        } else {
            const u16* src = (const u16*)W + woff + (size_t)(k0 + k) * ldw + n0 + tc4;
            uint2 u = *(const uint2*)src;
            T[tc4 + 0][k] = (u16)(u.x & 0xffffu); T[tc4 + 1][k] = (u16)(u.x >> 16);
            T[tc4 + 2][k] = (u16)(u.y & 0xffffu); T[tc4 + 3][k] = (u16)(u.y >> 16);
        }
    }
    __syncthreads();
#pragma unroll
    for (int i = 0; i < 4; i++) {
        int n = tr + i * 16;
        u32 w0 = (u32)T[n][tc4 + 0] | ((u32)T[n][tc4 + 1] << 16);
        u32 w1 = (u32)T[n][tc4 + 2] | ((u32)T[n][tc4 + 3] << 16);
        *(uint2*)(WT + (size_t)(n0 + n) * K + k0 + tc4) = make_uint2(w0, w1);
    }
}

// ---------------- LayerNorm ----------------
__global__ __launch_bounds__(256) void ln_kernel(const void* __restrict__ in,
                                                 size_t ioff, int sel,
                                                 const void* __restrict__ g,
                                                 const void* __restrict__ b,
                                                 u16* __restrict__ out,
                                                 const int* __restrict__ blk) {
    int wf = blk[0];
    int row = blockIdx.x, tid = threadIdx.x;
    size_t base = ioff + (size_t)row * EMBED;
    float v[3];
#pragma unroll
    for (int e = 0; e < 3; e++) {
        size_t idx = base + tid + e * 256;
        v[e] = (sel == 0) ? ((const float*)in)[idx] : wget(in, idx, wf);
    }
    float s = v[0] + v[1] + v[2];
    float q = v[0] * v[0] + v[1] * v[1] + v[2] * v[2];
#pragma unroll
    for (int off = 32; off > 0; off >>= 1) {
        s += __shfl_xor(s, off, 64);
        q += __shfl_xor(q, off, 64);
    }
    __shared__ float sb[8];
    int wid = tid >> 6, lane = tid & 63;
    if (lane == 0) { sb[wid] = s; sb[4 + wid] = q; }
    __syncthreads();
    if (tid == 0) {
        sb[0] = sb[0] + sb[1] + sb[2] + sb[3];
        sb[4] = sb[4] + sb[5] + sb[6] + sb[7];
    }
    __syncthreads();
    float mean = sb[0] * (1.0f / EMBED);
    float var  = sb[4] * (1.0f / EMBED) - mean * mean;
    float rs   = rsqrtf(var + 1e-5f);
    size_t obase = (size_t)row * EMBED;
#pragma unroll
    for (int e = 0; e < 3; e++) {
        int col = tid + e * 256;
        out[obase + col] = f2bf((v[e] - mean) * rs * wget(g, col, wf) + wget(b, col, wf));
    }
}

// ---------------- legacy VALU GEMM (tier-C fallback: handles N=192) ----------------
__global__ __launch_bounds__(256) void gemm_kernel(const u16* __restrict__ A,
                                                   const void* __restrict__ W,
                                                   size_t woff, int ldw,
                                                   const void* __restrict__ bias, int boff,
                                                   void* __restrict__ Cv, size_t coff,
                                                   int M, int N, int K, int flags,
                                                   int tcmode, const int* __restrict__ blk) {
    __shared__ float As[16][64];
    __shared__ float Bs[16][64];
    int wf = blk[0];
    int tid = threadIdx.x;
    int tx = tid & 15, ty = tid >> 4;
    int row0 = blockIdx.y * 64, col0 = blockIdx.x * 64;
    float acc[4][4] = {};
    int ar = tid >> 2, ac4 = tid & 3;
    int br = tid >> 4, bc4 = tid & 15;

    for (int kb = 0; kb < K; kb += 16) {
        {
            uint2 u = *(const uint2*)(A + (size_t)(row0 + ar) * K + kb + ac4 * 4);
            float a0, a1, a2, a3;
            unpack2(u.x, a0, a1); unpack2(u.y, a2, a3);
            As[ac4 * 4 + 0][ar] = a0; As[ac4 * 4 + 1][ar] = a1;
            As[ac4 * 4 + 2][ar] = a2; As[ac4 * 4 + 3][ar] = a3;
        }
        {
            size_t off = woff + (size_t)(kb + br) * ldw + col0 + bc4 * 4;
            if (wf) {
                float4 u = *(const float4*)((const float*)W + off);
                Bs[br][bc4 * 4 + 0] = u.x; Bs[br][bc4 * 4 + 1] = u.y;
                Bs[br][bc4 * 4 + 2] = u.z; Bs[br][bc4 * 4 + 3] = u.w;
            } else {
                uint2 u = *(const uint2*)((const u16*)W + off);
                float b0, b1, b2, b3;
                unpack2(u.x, b0, b1); unpack2(u.y, b2, b3);
                Bs[br][bc4 * 4 + 0] = b0; Bs[br][bc4 * 4 + 1] = b1;
                Bs[br][bc4 * 4 + 2] = b2; Bs[br][bc4 * 4 + 3] = b3;
            }
        }
        __syncthreads();
#pragma unroll
        for (int kk = 0; kk < 16; kk++) {
            float4 a = *(const float4*)&As[kk][ty * 4];
            float4 b = *(const float4*)&Bs[kk][tx * 4];
            float av[4] = {a.x, a.y, a.z, a.w};
            float bv[4] = {b.x, b.y, b.z, b.w};
#pragma unroll
            for (int i = 0; i < 4; i++)
#pragma unroll
                for (int j = 0; j < 4; j++)
                    acc[i][j] += av[i] * bv[j];
        }
        __syncthreads();
    }

#pragma unroll
    for (int i = 0; i < 4; i++) {
        int m = row0 + ty * 4 + i;
#pragma unroll
        for (int j = 0; j < 4; j++) {
            int n = col0 + tx * 4 + j;
            float v = acc[i][j];
            if (flags & 1) v += wget(bias, boff + n, wf);
            if (flags & 2) v = 0.5f * v * (1.0f + erff(v * 0.70710678118654752f));
            size_t idx = coff + (size_t)m * N + n;
            if (tcmode == 0) {
                ((float*)Cv)[idx] += v;
            } else if (tcmode == 1) {
                ((u16*)Cv)[idx] = f2bf(v);
            } else {
                if (wf) ((float*)Cv)[idx] += v;
                else { u16* p = (u16*)Cv; p[idx] = f2bf(v + bf2f(p[idx])); }
            }
        }
    }
}

// ---------------- MFMA GEMM (tier-B, reg-staged scatter B; legacy) ----------
__global__ __launch_bounds__(256) void gemm_mfma(const u16* __restrict__ A,
                                                 const void* __restrict__ W,
                                                 size_t woff, int ldw,
                                                 const void* __restrict__ bias, int boff,
                                                 void* __restrict__ Cv, size_t coff,
                                                 int M, int N, int K, int flags,
                                                 int tcmode, const int* __restrict__ blk) {
    __shared__ __align__(16) u16 As[128 * 32];
    __shared__ __align__(16) u16 Bs[128 * 32];
    int wf = blk[0];
    int tid = threadIdx.x;
    int wave = tid >> 6, lane = tid & 63;
    int x = lane & 15, g = lane >> 4;
    int wm = wave >> 1, wn = wave & 1;
    int row0 = blockIdx.y * 128, col0 = blockIdx.x * 128;

    int ar  = tid >> 1, ah = tid & 1;
    int bk  = tid >> 3, bn0 = (tid & 7) * 16;

    f32x4 acc[4][4];
#pragma unroll
    for (int i = 0; i < 4; i++)
#pragma unroll
        for (int j = 0; j < 4; j++) acc[i][j] = (f32x4){0.f, 0.f, 0.f, 0.f};

    for (int kb = 0; kb < K; kb += 32) {
        {
            const u16* asrc = A + (size_t)(row0 + ar) * K + kb + ah * 16;
            uint4 a0 = *(const uint4*)asrc;
            uint4 a1 = *(const uint4*)(asrc + 8);
            *(uint4*)&As[ar * 32 + bswz(ar, ah * 2 + 0)] = a0;
            *(uint4*)&As[ar * 32 + bswz(ar, ah * 2 + 1)] = a1;
        }
        {
            u16 bv[16];
            if (wf) {
                const float* wsrc = (const float*)W + woff + (size_t)(kb + bk) * ldw + col0 + bn0;
#pragma unroll
                for (int i = 0; i < 16; i += 4) {
                    float4 f = *(const float4*)(wsrc + i);
                    bv[i + 0] = f2bf(f.x); bv[i + 1] = f2bf(f.y);
                    bv[i + 2] = f2bf(f.z); bv[i + 3] = f2bf(f.w);
                }
            } else {
                const u16* wsrc = (const u16*)W + woff + (size_t)(kb + bk) * ldw + col0 + bn0;
                ((uint4*)bv)[0] = *(const uint4*)wsrc;
                ((uint4*)bv)[1] = *(const uint4*)(wsrc + 8);
            }
            int kg = bk >> 3, kl = bk & 7;
#pragma unroll
            for (int i = 0; i < 16; i++)
                Bs[(bn0 + i) * 32 + bswz(bn0 + i, kg) + kl] = bv[i];
        }
        __syncthreads();

        short8 af[4], bf[4];
#pragma unroll
        for (int mt = 0; mt < 4; mt++) {
            int r = wm * 64 + mt * 16 + x;
            af[mt] = *(const short8*)&As[r * 32 + bswz(r, g)];
        }
#pragma unroll
        for (int nt = 0; nt < 4; nt++) {
            int n = wn * 64 + nt * 16 + x;
            bf[nt] = *(const short8*)&Bs[n * 32 + bswz(n, g)];
        }
#pragma unroll
        for (int mt = 0; mt < 4; mt++)
#pragma unroll
            for (int nt = 0; nt < 4; nt++)
                acc[mt][nt] = __builtin_amdgcn_mfma_f32_16x16x32_bf16(af[mt], bf[nt], acc[mt][nt], 0, 0, 0);
        __syncthreads();
    }

#pragma unroll
    for (int mt = 0; mt < 4; mt++) {
#pragma unroll
        for (int nt = 0; nt < 4; nt++) {
#pragma unroll
            for (int r = 0; r < 4; r++) {
                int m = row0 + wm * 64 + mt * 16 + g * 4 + r;
                int n = col0 + wn * 64 + nt * 16 + x;
                float v = acc[mt][nt][r];
                if (flags & 1) v += wget(bias, boff + n, wf);
                if (flags & 2) v = 0.5f * v * (1.0f + erff(v * 0.70710678118654752f));
                size_t idx = coff + (size_t)m * N + n;
                if (tcmode == 0) {
                    ((float*)Cv)[idx] += v;
                } else if (tcmode == 1) {
                    ((u16*)Cv)[idx] = f2bf(v);
                } else {
                    if (wf) ((float*)Cv)[idx] += v;
                    else { u16* p = (u16*)Cv; p[idx] = f2bf(v + bf2f(p[idx])); }
                }
            }
        }
    }
}

// ---------------- MFMA GEMM v5: 64x128 tile, pre-transposed bf16 weights,
// global_load_lds staging, double-buffered, XCD-aware block swizzle (T1).
__global__ __launch_bounds__(256) void gemm_mfma_t(const u16* __restrict__ A,
                                                   const u16* __restrict__ BT,
                                                   const void* __restrict__ bias, int boff,
                                                   void* __restrict__ Cv, size_t coff,
                                                   int M, int N, int K, int flags,
                                                   int tcmode, const int* __restrict__ blk) {
    __shared__ __align__(16) u16 As[2][64 * 32];
    __shared__ __align__(16) u16 Bs[2][128 * 32];
    int wf = blk[0];
    int tid = threadIdx.x;
    int wave = tid >> 6, lane = tid & 63;
    int x = lane & 15, g = lane >> 4;
    int wm = wave >> 1, wn = wave & 1;
    int bx, by, bz;
    xcd_swz3(bx, by, bz);
    int row0 = by * 64, col0 = bx * 128;
    int KS = gridDim.z, kz = bz;
    int Kc = K / KS;

    // staging geometry: lane covers (row = wave*16 + lane/4, slot = lane&3)
    int l4 = lane >> 2, lg = lane & 3;
    int arow = wave * 16 + l4;
    int brow0 = arow;            // B rows 0..63
    int brow1 = 64 + arow;       // B rows 64..127
    const u16* agp  = A  + (size_t)(row0 + arow) * K + kz * Kc + (lg ^ cswz(arow))  * 8;
    const u16* bgp0 = BT + (size_t)(col0 + brow0) * K + kz * Kc + (lg ^ cswz(brow0)) * 8;
    const u16* bgp1 = BT + (size_t)(col0 + brow1) * K + kz * Kc + (lg ^ cswz(brow1)) * 8;

    int ra[2], rb[4];
#pragma unroll
    for (int mt = 0; mt < 2; mt++) {
        int r = wm * 32 + mt * 16 + x;
        ra[mt] = r * 32 + bswz(r, g);
    }
#pragma unroll
    for (int nt = 0; nt < 4; nt++) {
        int n = wn * 64 + nt * 16 + x;
        rb[nt] = n * 32 + bswz(n, g);
    }

    f32x4 acc[2][4];
#pragma unroll
    for (int i = 0; i < 2; i++)
#pragma unroll
        for (int j = 0; j < 4; j++) acc[i][j] = (f32x4){0.f, 0.f, 0.f, 0.f};

    int nsteps = Kc >> 5;

    load_lds16(agp,  &As[0][wave * 512]);
    load_lds16(bgp0, &Bs[0][wave * 512]);
    load_lds16(bgp1, &Bs[0][2048 + wave * 512]);
    __syncthreads();

    int cur = 0;
    for (int s = 0; s < nsteps; ++s) {
        bool nxt = (s + 1 < nsteps);
        if (nxt) {
            agp += 32; bgp0 += 32; bgp1 += 32;
            load_lds16(agp,  &As[cur ^ 1][wave * 512]);
            load_lds16(bgp0, &Bs[cur ^ 1][wave * 512]);
            load_lds16(bgp1, &Bs[cur ^ 1][2048 + wave * 512]);
        }
        short8 af[2], bfr[4];
#pragma unroll
        for (int mt = 0; mt < 2; mt++) af[mt] = *(const short8*)&As[cur][ra[mt]];
#pragma unroll
        for (int nt = 0; nt < 4; nt++) bfr[nt] = *(const short8*)&Bs[cur][rb[nt]];
#pragma unroll
        for (int mt = 0; mt < 2; mt++)
#pragma unroll
            for (int nt = 0; nt < 4; nt++)
                acc[mt][nt] = __builtin_amdgcn_mfma_f32_16x16x32_bf16(af[mt], bfr[nt], acc[mt][nt], 0, 0, 0);
        if (nxt) {
            __syncthreads();   // drains vmcnt -> next buffer fully landed
            cur ^= 1;
        }
    }

    bool kz0 = (kz == 0);
#pragma unroll
    for (int mt = 0; mt < 2; mt++) {
#pragma unroll
        for (int nt = 0; nt < 4; nt++) {
#pragma unroll
            for (int r = 0; r < 4; r++) {
                int m = row0 + wm * 32 + mt * 16 + g * 4 + r;
                int n = col0 + wn * 64 + nt * 16 + x;
                float v = acc[mt][nt][r];
                if ((flags & 1) && kz0) v += wget(bias, boff + n, wf);
                if (flags & 2) v = 0.5f * v * (1.0f + erff(v * 0.70710678118654752f));
                size_t idx = coff + (size_t)m * N + n;
                if (tcmode == 0) {
                    if (KS > 1) atomicAdd(&((float*)Cv)[idx], v);
                    else        ((float*)Cv)[idx] += v;
                } else if (tcmode == 1) {
                    ((u16*)Cv)[idx] = f2bf(v);
                } else {
                    if (wf) ((float*)Cv)[idx] += v;
                    else { u16* p = (u16*)Cv; p[idx] = f2bf(v + bf2f(p[idx])); }
                }
            }
        }
    }
}

// ---------------- flash attention (bf16 MFMA) ----------------
// Round-6 body (94.4 us) + XCD-aware block swizzle: grid (16,H,B) chunked so
// each XCD owns one batch -> K/V (3 MB self / 1.5 MB cross) stays resident in
// that XCD's 4 MB L2 instead of being re-missed to HBM by all 8 XCDs.
// In-place safe (AO == Q).
__global__ __launch_bounds__(256) void attn_kernel(const u16* __restrict__ Q,
                                                   const u16* __restrict__ K,
                                                   const u16* __restrict__ V,
                                                   u16* __restrict__ AO,
                                                   int ldq, int ldk, int ldv, int ldo,
                                                   size_t qss, size_t kss, size_t oss,
                                                   const int* __restrict__ blk,
                                                   int bfix, int Lk, int is_self) {
    int bxs, bys, bzs;
    xcd_swz3(bxs, bys, bzs);
    int bz   = (bfix < 0) ? bzs : 0;
    int bidx = (bfix < 0) ? bzs : bfix;
    const u16* Qp = Q + (size_t)bz * qss;
    const u16* Kp = K + (size_t)bz * kss;
    const u16* Vp = V + (size_t)bz * kss;
    u16* AOp = AO + (size_t)bz * oss;

    int hoff = bys * HDIM;
    int i0 = bxs * 64;
    int tid = threadIdx.x;
    int wave = tid >> 6, lane = tid & 63;
    int x = lane & 15, g = lane >> 4;

    int elb = blk[1 + bidx];
    int el_q = elb * blk[9];
    int el_k = is_self ? el_q : elb;

    __shared__ __align__(16) u16 Ks[64 * 96];
    __shared__ __align__(16) u16 Vs[96 * 64];
    __shared__ __align__(16) u16 Ps[4][16 * 72];

    short8 qf[3];
    {
        const u16* qrow = Qp + (size_t)(i0 + wave * 16 + x) * ldq + hoff;
#pragma unroll
        for (int kc = 0; kc < 3; kc++)
            qf[kc] = *(const short8*)(qrow + kc * 32 + g * 8);
    }

    const f32x4 zero4 = {0.f, 0.f, 0.f, 0.f};
    f32x4 o[6];
#pragma unroll
    for (int dt = 0; dt < 6; dt++) o[dt] = zero4;
    float m[4], l[4];
#pragma unroll
    for (int r = 0; r < 4; r++) { m[r] = NEG_MASK; l[r] = 0.f; }

    bool qok[4];
#pragma unroll
    for (int r = 0; r < 4; r++) qok[r] = (i0 + wave * 16 + g * 4 + r) < el_q;

    const float scale = 0.10206207261596576f;  // 1/sqrt(96)
    u16* pw = &Ps[wave][0];

    for (int kt0 = 0; kt0 < Lk; kt0 += 64) {
#pragma unroll
        for (int t = 0; t < 3; t++) {
            int idx = tid + t * 256;
            int j = idx / 12, c = idx % 12;
            *(uint4*)&Ks[j * 96 + c * 8] =
                *(const uint4*)(Kp + (size_t)(kt0 + j) * ldk + hoff + c * 8);
            uint4 vu = *(const uint4*)(Vp + (size_t)(kt0 + j) * ldv + hoff + c * 8);
            u16 vv[8] = {(u16)(vu.x & 0xffffu), (u16)(vu.x >> 16),
                         (u16)(vu.y & 0xffffu), (u16)(vu.y >> 16),
                         (u16)(vu.z & 0xffffu), (u16)(vu.z >> 16),
                         (u16)(vu.w & 0xffffu), (u16)(vu.w >> 16)};
            int jb = j >> 3, jl = j & 7;
#pragma unroll
            for (int ii = 0; ii < 8; ii++) {
                int d = c * 8 + ii;
                int sb = jb ^ (d & 7) ^ ((d >> 3) & 7);
                Vs[d * 64 + sb * 8 + jl] = vv[ii];
            }
        }
        __syncthreads();

        f32x4 st[4];
#pragma unroll
        for (int t = 0; t < 4; t++) {
            f32x4 acc = zero4;
#pragma unroll
            for (int kc = 0; kc < 3; kc++) {
                short8 kf = *(const short8*)&Ks[(t * 16 + x) * 96 + kc * 32 + g * 8];
                acc = __builtin_amdgcn_mfma_f32_16x16x32_bf16(qf[kc], kf, acc, 0, 0, 0);
            }
            st[t] = acc;
        }

#pragma unroll
        for (int t = 0; t < 4; t++) {
            bool kv_ok = (kt0 + t * 16 + x) < el_k;
#pragma unroll
            for (int r = 0; r < 4; r++)
                st[t][r] = (kv_ok && qok[r]) ? st[t][r] * scale : NEG_MASK;
        }

        float al[4];
#pragma unroll
        for (int r = 0; r < 4; r++) {
            float rm = fmaxf(fmaxf(st[0][r], st[1][r]), fmaxf(st[2][r], st[3][r]));
            rm = fmaxf(rm, __shfl_xor(rm, 1, 64));
            rm = fmaxf(rm, __shfl_xor(rm, 2, 64));
            rm = fmaxf(rm, __shfl_xor(rm, 4, 64));
            rm = fmaxf(rm, __shfl_xor(rm, 8, 64));
            float mn = fmaxf(m[r], rm);
            al[r] = __expf(m[r] - mn);
            m[r] = mn;
            l[r] *= al[r];
        }
#pragma unroll
        for (int dt = 0; dt < 6; dt++)
#pragma unroll
            for (int r = 0; r < 4; r++) o[dt][r] *= al[r];

#pragma unroll
        for (int t = 0; t < 4; t++)
#pragma unroll
            for (int r = 0; r < 4; r++) {
                float p = __expf(st[t][r] - m[r]);
                l[r] += p;
                pw[(g * 4 + r) * 72 + t * 16 + x] = f2bf(p);
            }

#pragma unroll
        for (int kc = 0; kc < 2; kc++) {
            short8 pf = *(const short8*)&pw[x * 72 + kc * 32 + g * 8];
#pragma unroll
            for (int dt = 0; dt < 6; dt++) {
                int d = dt * 16 + x;
                int sb = (kc * 4 + g) ^ (d & 7) ^ ((d >> 3) & 7);
                short8 vf = *(const short8*)&Vs[d * 64 + sb * 8];
                o[dt] = __builtin_amdgcn_mfma_f32_16x16x32_bf16(pf, vf, o[dt], 0, 0, 0);
            }
        }
        __syncthreads();
    }

    float inv[4];
#pragma unroll
    for (int r = 0; r < 4; r++) {
        float lr = l[r];
        lr += __shfl_xor(lr, 1, 64);
        lr += __shfl_xor(lr, 2, 64);
        lr += __shfl_xor(lr, 4, 64);
        lr += __shfl_xor(lr, 8, 64);
        inv[r] = 1.0f / lr;
    }
#pragma unroll
    for (int dt = 0; dt < 6; dt++)
#pragma unroll
        for (int r = 0; r < 4; r++) {
            size_t ob = (size_t)(i0 + wave * 16 + g * 4 + r) * ldo + hoff + dt * 16 + x;
            AOp[ob] = f2bf(o[dt][r] * inv[r]);
        }
}

// ---------------- launcher ----------------
extern "C" void kernel_launch(void* const* d_in, const int* in_sizes, int n_in,
                              void* d_out, int out_size, void* d_ws, size_t ws_size,
                              hipStream_t stream) {
    const void* x    = d_in[0];
    const void* c    = d_in[1];
    const int* el    = (const int*)d_in[2];
    const int* us    = (const int*)d_in[3];
    const void* Wq1  = d_in[4];
    const void* Wkv1 = d_in[5];
    const void* Wo1  = d_in[6];
    const void* bo1  = d_in[7];
    const void* Wq2  = d_in[8];
    const void* Wkv2 = d_in[9];
    const void* Wo2  = d_in[10];
    const void* bo2  = d_in[11];
    const void* g1 = d_in[12]; const void* b1 = d_in[13];
    const void* g2 = d_in[14]; const void* b2 = d_in[15];
    const void* g4 = d_in[16]; const void* b4 = d_in[17];
    const void* gc = d_in[18]; const void* bc = d_in[19];
    const void* Wf1 = d_in[20]; const void* bf1 = d_in[21];
    const void* Wf2 = d_in[22]; const void* bf2 = d_in[23];

    const int B = 8, S = 512, L = 1024, C = EMBED;
    const int NX = B * L * C;
    const size_t RL = (size_t)L * C;
    const size_t RS = (size_t)S * C;

    char* ws = (char*)d_ws;
    int*  blk = (int*)ws;
    dim3 blkd(256);

    bool tierA = ws_size >= (size_t)88080448;
    bool tierB = !tierA && ws_size >= (size_t)33030208;

    detect_kernel<<<1, 64, 0, stream>>>((const u16*)x, el, us, blk);

    if (tierA) {
        // Memory map (bytes from ws):
        //   64        X   (f32, 25165824)
        //   25165888  XN  (bf16, 12582912)
        //   37748800  WT  (bf16 weight pool, 9437184)
        //   47185984  P   (37748736): Qb+KVb | CNb+KV2b+Q2b | Hh
        // total 84934720 <= 88080448
        float* X  = (float*)(ws + 64);
        u16*   XN = (u16*)(ws + 25165888);
        u16*   WT = (u16*)(ws + 37748800);
        char*  P  = ws + 47185984;
        u16* Qb   = (u16*)P;
        u16* KVb  = (u16*)(P + 12582912);
        u16* CNb  = (u16*)P;
        u16* KV2b = (u16*)(P + 6291456);
        u16* Q2b  = (u16*)(P + 18874368);
        u16* Hh   = (u16*)P;
        // WT slot offsets (u16 units)
        const size_t WTq = 0, WTkv = 589824, WTo = 1769472;
        const size_t WTf1 = 0, WTf2 = 2359296;

        wire_to_f32<<<(NX + 255) / 256, blkd, 0, stream>>>(x, 0, X, NX, blk);

        // phase-1 weight transposes
        wtrans_kernel<<<dim3(12, 12), blkd, 0, stream>>>(Wq1, 0, C, C, WT + WTq, blk);
        wtrans_kernel<<<dim3(24, 12), blkd, 0, stream>>>(Wkv1, 0, 2 * C, C, WT + WTkv, blk);
        wtrans_kernel<<<dim3(12, 12), blkd, 0, stream>>>(Wo1, 0, C, C, WT + WTo, blk);

        ln_kernel<<<B * L, blkd, 0, stream>>>(X, 0, 0, g1, b1, XN, blk);
        gemm_mfma_t<<<dim3(6, 128, 1), blkd, 0, stream>>>(XN, WT + WTq, nullptr, 0, Qb, 0, B * L, C, C, 0, 1, blk);
        gemm_mfma_t<<<dim3(12, 128, 1), blkd, 0, stream>>>(XN, WT + WTkv, nullptr, 0, KVb, 0, B * L, 2 * C, C, 0, 1, blk);
        attn_kernel<<<dim3(16, 8, 8), blkd, 0, stream>>>(Qb, KVb, KVb + C, Qb, C, 2 * C, 2 * C, C,
                                                         RL, (size_t)L * 2 * C, RL, blk, -1, L, 1);
        gemm_mfma_t<<<dim3(6, 128, 1), blkd, 0, stream>>>(Qb, WT + WTo, bo1, 0, X, 0, B * L, C, C, 1, 0, blk);

        // phase-2 weight transposes (reuse slots after Wo1 gemm)
        wtrans_kernel<<<dim3(12, 12), blkd, 0, stream>>>(Wq2, 0, C, C, WT + WTq, blk);
        wtrans_kernel<<<dim3(24, 12), blkd, 0, stream>>>(Wkv2, 0, 2 * C, C, WT + WTkv, blk);
        wtrans_kernel<<<dim3(12, 12), blkd, 0, stream>>>(Wo2, 0, C, C, WT + WTo, blk);

        ln_kernel<<<B * L, blkd, 0, stream>>>(X, 0, 0, g2, b2, XN, blk);
        ln_kernel<<<B * S, blkd, 0, stream>>>(c, 0, 2, gc, bc, CNb, blk);
        gemm_mfma_t<<<dim3(12, 64, 1), blkd, 0, stream>>>(CNb, WT + WTkv, nullptr, 0, KV2b, 0, B * S, 2 * C, C, 0, 1, blk);
        gemm_mfma_t<<<dim3(6, 128, 1), blkd, 0, stream>>>(XN, WT + WTq, nullptr, 0, Q2b, 0, B * L, C, C, 0, 1, blk);
        attn_kernel<<<dim3(16, 8, 8), blkd, 0, stream>>>(Q2b, KV2b, KV2b + C, Q2b, C, 2 * C, 2 * C, C,
                                                         RL, (size_t)S * 2 * C, RL, blk, -1, S, 0);
        gemm_mfma_t<<<dim3(6, 128, 1), blkd, 0, stream>>>(Q2b, WT + WTo, bo2, 0, X, 0, B * L, C, C, 1, 0, blk);

        // FFN weight transposes
        wtrans_kernel<<<dim3(48, 12), blkd, 0, stream>>>(Wf1, 0, 4 * C, C, WT + WTf1, blk);
        wtrans_kernel<<<dim3(12, 48), blkd, 0, stream>>>(Wf2, 0, C, 4 * C, WT + WTf2, blk);

        ln_kernel<<<B * L, blkd, 0, stream>>>(X, 0, 0, g4, b4, XN, blk);
        for (int h = 0; h < 2; h++) {
            size_t ro = (size_t)h * 4096 * C;
            gemm_mfma_t<<<dim3(24, 64, 1), blkd, 0, stream>>>(XN + ro, WT + WTf1, bf1, 0, Hh, 0, 4096, 4 * C, C, 1 | 2, 1, blk);
            gemm_mfma_t<<<dim3(6, 64, 2), blkd, 0, stream>>>(Hh, WT + WTf2, bf2, 0, X, ro, 4096, C, 4 * C, 1, 0, blk);
        }

        f32_to_out<<<(NX + 255) / 256, blkd, 0, stream>>>(X, d_out, 0, NX, blk);
    } else if (tierB) {
        float* X  = (float*)(ws + 64);
        u16*   XN = (u16*)(ws + 64 + 25165824);
        char*  P  = ws + 64 + 25165824 + 1572864;
        u16* Qb   = (u16*)P;
        u16* KVb  = (u16*)(P + 1572864);
        u16* AOb  = (u16*)(P + 4718592);
        u16* CNb  = (u16*)P;
        u16* KV2b = (u16*)(P + 786432);
        u16* Q2b  = (u16*)(P + 2359296);
        u16* AO2b = (u16*)(P + 3932160);
        u16* Hb   = (u16*)P;

        wire_to_f32<<<(NX + 255) / 256, blkd, 0, stream>>>(x, 0, X, NX, blk);

        for (int b = 0; b < B; b++) {
            size_t ro = (size_t)b * RL;
            ln_kernel<<<L, blkd, 0, stream>>>(X, ro, 0, g1, b1, XN, blk);
            gemm_mfma<<<dim3(6, 8), blkd, 0, stream>>>(XN, Wq1, 0, C, nullptr, 0, Qb, 0, L, C, C, 0, 1, blk);
            gemm_mfma<<<dim3(12, 8), blkd, 0, stream>>>(XN, Wkv1, 0, 2 * C, nullptr, 0, KVb, 0, L, 2 * C, C, 0, 1, blk);
            attn_kernel<<<dim3(16, 8), blkd, 0, stream>>>(Qb, KVb, KVb + C, AOb, C, 2 * C, 2 * C, C, 0, 0, 0, blk, b, L, 1);
            gemm_mfma<<<dim3(6, 8), blkd, 0, stream>>>(AOb, Wo1, 0, C, bo1, 0, X, ro, L, C, C, 1, 0, blk);

            ln_kernel<<<L, blkd, 0, stream>>>(X, ro, 0, g2, b2, XN, blk);
            ln_kernel<<<S, blkd, 0, stream>>>(c, (size_t)b * RS, 2, gc, bc, CNb, blk);
            gemm_mfma<<<dim3(12, 4), blkd, 0, stream>>>(CNb, Wkv2, 0, 2 * C, nullptr, 0, KV2b, 0, S, 2 * C, C, 0, 1, blk);
            gemm_mfma<<<dim3(6, 8), blkd, 0, stream>>>(XN, Wq2, 0, C, nullptr, 0, Q2b, 0, L, C, C, 0, 1, blk);
            attn_kernel<<<dim3(16, 8), blkd, 0, stream>>>(Q2b, KV2b, KV2b + C, AO2b, C, 2 * C, 2 * C, C, 0, 0, 0, blk, b, S, 0);
            gemm_mfma<<<dim3(6, 8), blkd, 0, stream>>>(AO2b, Wo2, 0, C, bo2, 0, X, ro, L, C, C, 1, 0, blk);

            ln_kernel<<<L, blkd, 0, stream>>>(X, ro, 0, g4, b4, XN, blk);
            gemm_mfma<<<dim3(24, 8), blkd, 0, stream>>>(XN, Wf1, 0, 4 * C, bf1, 0, Hb, 0, L, 4 * C, C, 1 | 2, 1, blk);
            gemm_mfma<<<dim3(6, 8), blkd, 0, stream>>>(Hb, Wf2, 0, C, bf2, 0, X, ro, L, C, 4 * C, 1, 0, blk);
        }
        f32_to_out<<<(NX + 255) / 256, blkd, 0, stream>>>(X, d_out, 0, NX, blk);
    } else {
        u16*  XN  = (u16*)(ws + 64);
        u16*  CNb = (u16*)(ws + 64 + 1572864);
        char* P2  = ws + 64 + 1572864 + 786432;
        u16* Qp  = (u16*)P2;
        u16* Kp  = (u16*)(P2 + 393216);
        u16* Vp  = (u16*)(P2 + 786432);
        u16* AOp = (u16*)(P2 + 1179648);
        u16* Hc  = (u16*)P2;

        wire_copy<<<(NX + 255) / 256, blkd, 0, stream>>>(x, d_out, NX, blk);

        for (int b = 0; b < B; b++) {
            size_t ro = (size_t)b * RL;

            ln_kernel<<<L, blkd, 0, stream>>>(d_out, ro, 2, g1, b1, XN, blk);
            for (int p = 0; p < 4; p++) {
                int h = 2 * p;
                gemm_kernel<<<dim3(3, 16), blkd, 0, stream>>>(XN, Wq1, (size_t)h * 96, C, nullptr, 0, Qp, 0, L, 192, C, 0, 1, blk);
                gemm_kernel<<<dim3(3, 16), blkd, 0, stream>>>(XN, Wkv1, (size_t)h * 96, 2 * C, nullptr, 0, Kp, 0, L, 192, C, 0, 1, blk);
                gemm_kernel<<<dim3(3, 16), blkd, 0, stream>>>(XN, Wkv1, (size_t)(C + h * 96), 2 * C, nullptr, 0, Vp, 0, L, 192, C, 0, 1, blk);
                attn_kernel<<<dim3(16, 2), blkd, 0, stream>>>(Qp, Kp, Vp, AOp, 192, 192, 192, 192, 0, 0, 0, blk, b, L, 1);
                gemm_kernel<<<dim3(12, 16), blkd, 0, stream>>>(AOp, Wo1, (size_t)h * 96 * C, C, bo1, 0, d_out, ro, L, C, 192, (p == 0) ? 1 : 0, 3, blk);
            }
            ln_kernel<<<L, blkd, 0, stream>>>(d_out, ro, 2, g2, b2, XN, blk);
            ln_kernel<<<S, blkd, 0, stream>>>(c, (size_t)b * RS, 2, gc, bc, CNb, blk);
            for (int p = 0; p < 4; p++) {
                int h = 2 * p;
                gemm_kernel<<<dim3(3, 16), blkd, 0, stream>>>(XN, Wq2, (size_t)h * 96, C, nullptr, 0, Qp, 0, L, 192, C, 0, 1, blk);
                gemm_kernel<<<dim3(3, 8), blkd, 0, stream>>>(CNb, Wkv2, (size_t)h * 96, 2 * C, nullptr, 0, Kp, 0, S, 192, C, 0, 1, blk);
                gemm_kernel<<<dim3(3, 8), blkd, 0, stream>>>(CNb, Wkv2, (size_t)(C + h * 96), 2 * C, nullptr, 0, Vp, 0, S, 192, C, 0, 1, blk);
                attn_kernel<<<dim3(16, 2), blkd, 0, stream>>>(Qp, Kp, Vp, AOp, 192, 192, 192, 192, 0, 0, 0, blk, b, S, 0);
                gemm_kernel<<<dim3(12, 16), blkd, 0, stream>>>(AOp, Wo2, (size_t)h * 96 * C, C, bo2, 0, d_out, ro, L, C, 192, (p == 0) ? 1 : 0, 3, blk);
            }
            ln_kernel<<<L, blkd, 0, stream>>>(d_out, ro, 2, g4, b4, XN, blk);
            for (int ch = 0; ch < 4; ch++) {
                gemm_kernel<<<dim3(12, 16), blkd, 0, stream>>>(XN, Wf1, (size_t)ch * C, 4 * C, bf1, ch * C, Hc, 0, L, C, C, 1 | 2, 1, blk);
                gemm_kernel<<<dim3(12, 16), blkd, 0, stream>>>(Hc, Wf2, (size_t)ch * C * C, C, bf2, 0, d_out, ro, L, C, C, (ch == 0) ? 1 : 0, 3, blk);
            }
        }
    }
}